// Round 7
// baseline (277.038 us; speedup 1.0000x reference)
//
#include <hip/hip_runtime.h>
#include <float.h>

// Model constants: N=20000, E=320000, F_IN=256, HID=32, HEADS=8, EDGE_DIM=8

typedef short v8s __attribute__((ext_vector_type(8)));
typedef float v4f __attribute__((ext_vector_type(4)));

__device__ __forceinline__ ushort f2bf(float f) {
  unsigned u = __float_as_uint(f);
  u = (u + 0x7FFF + ((u >> 16) & 1)) >> 16;
  return (ushort)u;
}
__device__ __forceinline__ float bf2f(ushort h) {
  return __uint_as_float(((unsigned)h) << 16);
}

// ---------------------------------------------------------------- CSR build
__global__ __launch_bounds__(1024) void k_scan(const int* __restrict__ deg,
                                               int* __restrict__ row_ptr, int N) {
  __shared__ int part[1024];
  int tid = threadIdx.x;
  int chunk = (N + 1023) / 1024;
  int lo = tid * chunk;
  if (lo > N) lo = N;
  int hi = lo + chunk;
  if (hi > N) hi = N;
  int s = 0;
  for (int i = lo; i < hi; i++) s += deg[i] + 1;
  part[tid] = s;
  __syncthreads();
  for (int off = 1; off < 1024; off <<= 1) {
    int v = 0;
    if (tid >= off) v = part[tid - off];
    __syncthreads();
    part[tid] += v;
    __syncthreads();
  }
  int base = part[tid] - s;  // exclusive prefix
  for (int i = lo; i < hi; i++) { row_ptr[i] = base; base += deg[i] + 1; }
  if (tid == 1023) row_ptr[N] = part[1023];
}

// Scatter edges + self loops into CSR order by dst. 8 B payload per entry.
// Self loop gets eid = E + n (its aed slot is filled by k_selfmean).
__global__ void k_scatter(const int* __restrict__ src, const int* __restrict__ dst,
                          const int* __restrict__ row_ptr, int* __restrict__ cursor,
                          int* __restrict__ csr_src, int* __restrict__ csr_eid,
                          int E, int N) {
  int i = blockIdx.x * blockDim.x + threadIdx.x;
  if (i >= E + N) return;
  int s, d;
  if (i < E) { s = src[i]; d = dst[i]; }
  else       { s = d = i - E; }
  int pos = row_ptr[d] + atomicAdd(&cursor[d], 1);
  csr_src[pos] = s;
  csr_eid[pos] = i;
}

// ------------------------------------- prep (block 64) + W1 transpose (blocks 0-63)
__global__ __launch_bounds__(256) void k_prep_trans(const float* __restrict__ W1,
                                                    const float* __restrict__ We1,
                                                    const float* __restrict__ ae1,
                                                    const float* __restrict__ We2,
                                                    const float* __restrict__ ae2,
                                                    ushort* __restrict__ Bt,
                                                    float* __restrict__ M1,
                                                    float* __restrict__ m2) {
  if (blockIdx.x == 64) {
    int t = threadIdx.x;
    if (t < 64) {
      int k = t >> 3, h = t & 7;
      float s = 0.f;
      for (int c = 0; c < 32; c++) s += We1[k * 256 + h * 32 + c] * ae1[h * 32 + c];
      M1[k * 8 + h] = s;
    } else if (t < 72) {
      int k = t - 64;
      float s = 0.f;
      for (int c = 0; c < 32; c++) s += We2[k * 32 + c] * ae2[c];
      m2[k] = s;
    }
    return;
  }
  __shared__ float tile[32][33];
  int bx = blockIdx.x & 7, by = blockIdx.x >> 3;
  int tx = threadIdx.x & 31, ty = threadIdx.x >> 5;
  for (int r = ty; r < 32; r += 8)
    tile[r][tx] = W1[(size_t)(by * 32 + r) * 256 + bx * 32 + tx];
  __syncthreads();
  for (int r = ty; r < 32; r += 8)
    Bt[(size_t)(bx * 32 + r) * 256 + by * 32 + tx] = f2bf(tile[tx][r]);
}

// ------------------------------- fused edge logits + degree count (one pass)
__global__ void k_edge_fused(const float* __restrict__ ea, const int* __restrict__ dst,
                             const float* __restrict__ Wse, const float* __restrict__ bse,
                             const float* __restrict__ M1, const float* __restrict__ m2,
                             float* __restrict__ aed1, float* __restrict__ aed2,
                             int* __restrict__ deg, int E) {
  __shared__ float sW[16], sb[8], sM[64], sm2[8];
  int t = threadIdx.x;
  if (t < 16) sW[t] = Wse[t];
  if (t < 8) sb[t] = bse[t];
  if (t < 64) sM[t] = M1[t];
  if (t >= 64 && t < 72) sm2[t - 64] = m2[t - 64];
  __syncthreads();
  int e = blockIdx.x * blockDim.x + t;
  if (e >= E) return;
  atomicAdd(&deg[dst[e]], 1);
  float2 av = ((const float2*)ea)[e];
  float e8[8];
#pragma unroll
  for (int k = 0; k < 8; k++)
    e8[k] = fmaxf(av.x * sW[k] + av.y * sW[8 + k] + sb[k], 0.f);
  float o[8];
#pragma unroll
  for (int h = 0; h < 8; h++) {
    float s = 0.f;
#pragma unroll
    for (int k = 0; k < 8; k++) s += e8[k] * sM[k * 8 + h];
    o[h] = s;
  }
  *(float4*)(aed1 + (size_t)e * 8)     = make_float4(o[0], o[1], o[2], o[3]);
  *(float4*)(aed1 + (size_t)e * 8 + 4) = make_float4(o[4], o[5], o[6], o[7]);
  float s2 = 0.f;
#pragma unroll
  for (int k = 0; k < 8; k++) s2 += e8[k] * sm2[k];
  aed2[e] = s2;
}

// Self-loop logits appended at aed[E+n]: mean of the row's real-edge logits.
__global__ void k_selfmean(const int* __restrict__ row_ptr, const int* __restrict__ csr_eid,
                           float* __restrict__ aed1, float* __restrict__ aed2,
                           int E, int N) {
  int i = blockIdx.x * blockDim.x + threadIdx.x;
  if (i >= N * 8) return;
  int n = i >> 3, h = i & 7;
  int begin = row_ptr[n], end = row_ptr[n + 1];
  int deg = end - begin - 1;
  float inv = 1.f / (float)(deg > 1 ? deg : 1);
  float s = 0.f, s2 = 0.f;
  for (int p = begin; p < end; p++) {
    int eid = csr_eid[p];
    if (eid < E) {
      s += aed1[(size_t)eid * 8 + h];
      if (h == 0) s2 += aed2[eid];
    }
  }
  aed1[(size_t)(E + n) * 8 + h] = s * inv;
  if (h == 0) aed2[E + n] = s2 * inv;
}

// ---------------------------------------------------------------- GEMM1 (MFMA bf16)
// h1b = bf16(x @ W1); fused attn1 epilogue.
__global__ __launch_bounds__(256) void k_gemm1_mfma(const float* __restrict__ A,
                                                    const ushort* __restrict__ Bt,
                                                    const float* __restrict__ as1,
                                                    const float* __restrict__ ad1,
                                                    ushort* __restrict__ h1b,
                                                    float* __restrict__ asv,
                                                    float* __restrict__ adv, int M) {
  __shared__ ushort sA[64 * 40];   // [row][k] bf16, stride 40
  __shared__ ushort sB[256 * 40];  // [col][k] bf16, stride 40
  __shared__ float sas[256], sad[256];
  int t = threadIdx.x;
  int wave = t >> 6, lane = t & 63;
  int m0 = blockIdx.x * 64;
  int c = lane & 15, kg = lane >> 4;
  sas[t] = as1[t];
  sad[t] = ad1[t];
  v4f acc[4][4];
#pragma unroll
  for (int a = 0; a < 4; a++)
#pragma unroll
    for (int b = 0; b < 4; b++) acc[a][b] = (v4f)(0.f);
  int arow = t >> 2;
  int akoff = (t & 3) * 8;
  bool aval = (m0 + arow) < M;
  const float* aptr = A + (size_t)(m0 + arow) * 256 + akoff;
  const ushort* bptr = Bt + (size_t)t * 256;
  for (int k0 = 0; k0 < 256; k0 += 32) {
    float4 v0 = make_float4(0.f, 0.f, 0.f, 0.f), v1 = v0;
    if (aval) { v0 = *(const float4*)(aptr + k0); v1 = *(const float4*)(aptr + k0 + 4); }
    ushort* dst = &sA[arow * 40 + akoff];
    dst[0] = f2bf(v0.x); dst[1] = f2bf(v0.y); dst[2] = f2bf(v0.z); dst[3] = f2bf(v0.w);
    dst[4] = f2bf(v1.x); dst[5] = f2bf(v1.y); dst[6] = f2bf(v1.z); dst[7] = f2bf(v1.w);
    *(v8s*)&sB[t * 40 + 0]  = *(const v8s*)(bptr + k0 + 0);
    *(v8s*)&sB[t * 40 + 8]  = *(const v8s*)(bptr + k0 + 8);
    *(v8s*)&sB[t * 40 + 16] = *(const v8s*)(bptr + k0 + 16);
    *(v8s*)&sB[t * 40 + 24] = *(const v8s*)(bptr + k0 + 24);
    __syncthreads();
    v8s af[4], bfr[4];
#pragma unroll
    for (int mt = 0; mt < 4; mt++) af[mt] = *(v8s*)&sA[(mt * 16 + c) * 40 + kg * 8];
#pragma unroll
    for (int nt = 0; nt < 4; nt++) bfr[nt] = *(v8s*)&sB[(wave * 64 + nt * 16 + c) * 40 + kg * 8];
#pragma unroll
    for (int mt = 0; mt < 4; mt++)
#pragma unroll
      for (int nt = 0; nt < 4; nt++)
        acc[mt][nt] = __builtin_amdgcn_mfma_f32_16x16x32_bf16(af[mt], bfr[nt], acc[mt][nt], 0, 0, 0);
    __syncthreads();
  }
  // C/D layout: col = lane&15 (=c), row = kg*4 + reg
  int colbase = wave * 64;
#pragma unroll
  for (int mt = 0; mt < 4; mt++) {
#pragma unroll
    for (int i = 0; i < 4; i++) {
      int m = m0 + mt * 16 + kg * 4 + i;
      if (m < M) {
#pragma unroll
        for (int nt = 0; nt < 4; nt++)
          h1b[(size_t)m * 256 + colbase + nt * 16 + c] = f2bf(acc[mt][nt][i]);
      }
      float s1a = acc[mt][0][i] * sas[colbase + c]      + acc[mt][1][i] * sas[colbase + 16 + c];
      float s2a = acc[mt][0][i] * sad[colbase + c]      + acc[mt][1][i] * sad[colbase + 16 + c];
      float s1b = acc[mt][2][i] * sas[colbase + 32 + c] + acc[mt][3][i] * sas[colbase + 48 + c];
      float s2b = acc[mt][2][i] * sad[colbase + 32 + c] + acc[mt][3][i] * sad[colbase + 48 + c];
#pragma unroll
      for (int o = 1; o < 16; o <<= 1) {
        s1a += __shfl_xor(s1a, o);
        s2a += __shfl_xor(s2a, o);
        s1b += __shfl_xor(s1b, o);
        s2b += __shfl_xor(s2b, o);
      }
      if (c == 0 && m < M) {
        asv[(size_t)m * 8 + 2 * wave]     = s1a;
        adv[(size_t)m * 8 + 2 * wave]     = s2a;
        asv[(size_t)m * 8 + 2 * wave + 1] = s1b;
        adv[(size_t)m * 8 + 2 * wave + 1] = s2b;
      }
    }
  }
}

// ------------------------------------------------- conv1: one wave per node (LDS-staged)
// Online softmax, 8 heads; aed gathered via csr_eid. h2b = bf16(relu(out + b1)).
__global__ __launch_bounds__(64) void k_conv1(
    const int* __restrict__ row_ptr, const int* __restrict__ csr_src,
    const int* __restrict__ csr_eid, const float* __restrict__ aed1,
    const float* __restrict__ asv, const float* __restrict__ adv,
    const ushort* __restrict__ h1b, const float* __restrict__ b1,
    ushort* __restrict__ h2b, int N) {
  int n = blockIdx.x;
  int lane = threadIdx.x;
  int h = lane >> 3;
  int sub = lane & 7;
  __shared__ float sw[64 * 8];
  __shared__ int ssrc[64], seid[64];
  __shared__ float sm[8], sl[8], sadv[8];
  int begin = row_ptr[n], end = row_ptr[n + 1];
  if (lane < 8) { sm[lane] = -FLT_MAX; sl[lane] = 0.f; sadv[lane] = adv[(size_t)n * 8 + lane]; }
  float4 acc = make_float4(0.f, 0.f, 0.f, 0.f);
  for (int cs = begin; cs < end; cs += 64) {
    int c = min(64, end - cs);
    __syncthreads();
    if (lane < c) { ssrc[lane] = csr_src[cs + lane]; seid[lane] = csr_eid[cs + lane]; }
    __syncthreads();
    for (int idx = lane; idx < c * 8; idx += 64) {
      int el = idx >> 3, hh = idx & 7;
      float a = asv[(size_t)ssrc[el] * 8 + hh] + sadv[hh] +
                aed1[(size_t)seid[el] * 8 + hh];
      a = a > 0.f ? a : 0.2f * a;
      sw[idx] = a;
    }
    __syncthreads();
    float mloc = -FLT_MAX;
    for (int el = sub; el < c; el += 8) mloc = fmaxf(mloc, sw[el * 8 + h]);
#pragma unroll
    for (int o = 1; o < 8; o <<= 1) mloc = fmaxf(mloc, __shfl_xor(mloc, o));
    float mold = sm[h];
    float mnew = fmaxf(mold, mloc);
    float scale = __expf(mold - mnew);
    float lloc = 0.f;
    for (int el = sub; el < c; el += 8) {
      float w = __expf(sw[el * 8 + h] - mnew);
      sw[el * 8 + h] = w;
      lloc += w;
    }
#pragma unroll
    for (int o = 1; o < 8; o <<= 1) lloc += __shfl_xor(lloc, o);
    __syncthreads();
    if (sub == 0) { sm[h] = mnew; sl[h] = sl[h] * scale + lloc; }
    acc.x *= scale; acc.y *= scale; acc.z *= scale; acc.w *= scale;
    for (int el = 0; el < c; el++) {
      float w = sw[el * 8 + h];
      ushort4 hv = *(const ushort4*)(h1b + (size_t)ssrc[el] * 256 + lane * 4);
      acc.x += w * bf2f(hv.x);
      acc.y += w * bf2f(hv.y);
      acc.z += w * bf2f(hv.z);
      acc.w += w * bf2f(hv.w);
    }
  }
  __syncthreads();
  float inv = 1.f / (sl[h] + 1e-16f);
  float4 bv = *(const float4*)(b1 + lane * 4);
  ushort4 o4;
  o4.x = f2bf(fmaxf(acc.x * inv + bv.x, 0.f));
  o4.y = f2bf(fmaxf(acc.y * inv + bv.y, 0.f));
  o4.z = f2bf(fmaxf(acc.z * inv + bv.z, 0.f));
  o4.w = f2bf(fmaxf(acc.w * inv + bv.w, 0.f));
  *(ushort4*)(h2b + (size_t)n * 256 + lane * 4) = o4;
}

// g2 = h2 @ W2 (256 -> 32), 8 nodes/block; fused asv2/adv2 epilogue.
__global__ __launch_bounds__(256) void k_gemm2(const ushort* __restrict__ h2b,
                                               const float* __restrict__ W2,
                                               const float* __restrict__ as2,
                                               const float* __restrict__ ad2,
                                               float* __restrict__ g2,
                                               float* __restrict__ asv2,
                                               float* __restrict__ adv2, int N) {
  __shared__ float xs[8 * 256];
  __shared__ float sas[32], sad[32];
  int t = threadIdx.x;
  if (t < 32) { sas[t] = as2[t]; sad[t] = ad2[t]; }
  int n0 = blockIdx.x * 8;
  for (int idx = t; idx < 8 * 256; idx += 256) {
    int node = n0 + (idx >> 8);
    xs[idx] = (node < N) ? bf2f(h2b[(size_t)node * 256 + (idx & 255)]) : 0.f;
  }
  __syncthreads();
  int j = t >> 5, cc = t & 31;
  int node = n0 + j;
  float acc = 0.f;
#pragma unroll 8
  for (int k = 0; k < 256; k++) acc += xs[j * 256 + k] * W2[k * 32 + cc];
  float s1 = acc * sas[cc], s2 = acc * sad[cc];
#pragma unroll
  for (int o = 1; o < 32; o <<= 1) {
    s1 += __shfl_xor(s1, o);
    s2 += __shfl_xor(s2, o);
  }
  if (node < N) {
    g2[(size_t)node * 32 + cc] = acc;
    if (cc == 0) { asv2[node] = s1; adv2[node] = s2; }
  }
}

// ------------------------------------------------- conv2: one wave per node (LDS-staged)
__global__ __launch_bounds__(64) void k_conv2(
    const int* __restrict__ row_ptr, const int* __restrict__ csr_src,
    const int* __restrict__ csr_eid, const float* __restrict__ aed2,
    const float* __restrict__ asv2, const float* __restrict__ adv2,
    const float* __restrict__ g2, const float* __restrict__ b2,
    float* __restrict__ out, int N) {
  int n = blockIdx.x;
  int lane = threadIdx.x;
  int sub = lane >> 3, q = lane & 7;
  __shared__ float sw[64];
  __shared__ int ssrc[64];
  int begin = row_ptr[n], end = row_ptr[n + 1];
  float advn = adv2[n];
  float m = -FLT_MAX, l = 0.f;
  float4 acc = make_float4(0.f, 0.f, 0.f, 0.f);
  for (int cs = begin; cs < end; cs += 64) {
    int c = min(64, end - cs);
    __syncthreads();
    float a = -FLT_MAX;
    if (lane < c) {
      int s = csr_src[cs + lane];
      ssrc[lane] = s;
      int eid = csr_eid[cs + lane];
      a = asv2[s] + advn + aed2[eid];
      a = a > 0.f ? a : 0.2f * a;
    }
    float cm = a;
#pragma unroll
    for (int o = 1; o < 64; o <<= 1) cm = fmaxf(cm, __shfl_xor(cm, o));
    float nm = fmaxf(m, cm);
    float sc = __expf(m - nm);
    float w = (lane < c) ? __expf(a - nm) : 0.f;
    float cl = w;
#pragma unroll
    for (int o = 1; o < 64; o <<= 1) cl += __shfl_xor(cl, o);
    l = l * sc + cl;
    m = nm;
    sw[lane] = w;
    __syncthreads();
    acc.x *= sc; acc.y *= sc; acc.z *= sc; acc.w *= sc;
    for (int el = sub; el < c; el += 8) {
      float w2 = sw[el];
      const float4 gv = *(const float4*)(g2 + (size_t)ssrc[el] * 32 + q * 4);
      acc.x += w2 * gv.x; acc.y += w2 * gv.y; acc.z += w2 * gv.z; acc.w += w2 * gv.w;
    }
  }
#pragma unroll
  for (int o = 8; o < 64; o <<= 1) {
    acc.x += __shfl_xor(acc.x, o);
    acc.y += __shfl_xor(acc.y, o);
    acc.z += __shfl_xor(acc.z, o);
    acc.w += __shfl_xor(acc.w, o);
  }
  if (lane < 8) {
    float inv = 1.f / (l + 1e-16f);
    float4 bv = *(const float4*)(b2 + lane * 4);
    float4 o4;
    o4.x = acc.x * inv + bv.x;
    o4.y = acc.y * inv + bv.y;
    o4.z = acc.z * inv + bv.z;
    o4.w = acc.w * inv + bv.w;
    *(float4*)(out + (size_t)n * 32 + lane * 4) = o4;
  }
}

// ---------------------------------------------------------------- launch
extern "C" void kernel_launch(void* const* d_in, const int* in_sizes, int n_in,
                              void* d_out, int out_size, void* d_ws, size_t ws_size,
                              hipStream_t stream) {
  (void)n_in; (void)out_size; (void)ws_size;
  const float* x   = (const float*)d_in[0];
  const int*   ei  = (const int*)d_in[1];
  const float* ea  = (const float*)d_in[2];
  const float* Wse = (const float*)d_in[3];
  const float* bse = (const float*)d_in[4];
  const float* W1  = (const float*)d_in[5];
  const float* as1 = (const float*)d_in[6];
  const float* ad1 = (const float*)d_in[7];
  const float* We1 = (const float*)d_in[8];
  const float* ae1 = (const float*)d_in[9];
  const float* b1  = (const float*)d_in[10];
  const float* W2  = (const float*)d_in[11];
  const float* as2 = (const float*)d_in[12];
  const float* ad2 = (const float*)d_in[13];
  const float* We2 = (const float*)d_in[14];
  const float* ae2 = (const float*)d_in[15];
  const float* b2  = (const float*)d_in[16];
  const int N = in_sizes[0] / 256;
  const int E = in_sizes[1] / 2;
  const int* src = ei;
  const int* dst = ei + E;

  char* base = (char*)d_ws;
  size_t off = 0;
  auto alloc = [&](size_t bytes) -> char* {
    off = (off + 255) & ~(size_t)255;
    char* p = base + off;
    off += bytes;
    return p;
  };
  int*   deg      = (int*)alloc((size_t)N * 4);
  int*   cursor   = (int*)alloc((size_t)N * 4);
  size_t zero_bytes = (size_t)((char*)(cursor + N) - (char*)deg);
  int* row_ptr    = (int*)alloc((size_t)(N + 1) * 4);
  int* csr_src    = (int*)alloc((size_t)(E + N) * 4);
  int* csr_eid    = (int*)alloc((size_t)(E + N) * 4);
  float* aed1_lin = (float*)alloc((size_t)(E + N) * 8 * 4);
  float* aed2_lin = (float*)alloc((size_t)(E + N) * 4);
  ushort* W1T     = (ushort*)alloc((size_t)256 * 256 * 2);
  ushort* h1b     = (ushort*)alloc((size_t)N * 256 * 2);
  float* asv1     = (float*)alloc((size_t)N * 8 * 4);
  float* adv1     = (float*)alloc((size_t)N * 8 * 4);
  ushort* h2b     = (ushort*)alloc((size_t)N * 256 * 2);
  float* g2       = (float*)alloc((size_t)N * 32 * 4);
  float* asv2     = (float*)alloc((size_t)N * 4);
  float* adv2     = (float*)alloc((size_t)N * 4);
  float* M1       = (float*)alloc(64 * 4);
  float* m2       = (float*)alloc(8 * 4);

  hipMemsetAsync(deg, 0, zero_bytes, stream);
  k_prep_trans<<<65, 256, 0, stream>>>(W1, We1, ae1, We2, ae2, W1T, M1, m2);
  k_edge_fused<<<(E + 255) / 256, 256, 0, stream>>>(ea, dst, Wse, bse, M1, m2,
                                                    aed1_lin, aed2_lin, deg, E);
  k_scan<<<1, 1024, 0, stream>>>(deg, row_ptr, N);
  k_scatter<<<(E + N + 255) / 256, 256, 0, stream>>>(src, dst, row_ptr, cursor,
                                                     csr_src, csr_eid, E, N);
  k_selfmean<<<(N * 8 + 255) / 256, 256, 0, stream>>>(row_ptr, csr_eid,
                                                      aed1_lin, aed2_lin, E, N);
  k_gemm1_mfma<<<(N + 63) / 64, 256, 0, stream>>>(x, W1T, as1, ad1, h1b, asv1, adv1, N);
  k_conv1<<<N, 64, 0, stream>>>(row_ptr, csr_src, csr_eid, aed1_lin, asv1, adv1, h1b, b1, h2b, N);
  k_gemm2<<<(N + 7) / 8, 256, 0, stream>>>(h2b, W2, as2, ad2, g2, asv2, adv2, N);
  k_conv2<<<N, 64, 0, stream>>>(row_ptr, csr_src, csr_eid, aed2_lin, asv2, adv2, g2, b2,
                                (float*)d_out, N);
}

// Round 8
// 258.338 us; speedup vs baseline: 1.0724x; 1.0724x over previous
//
#include <hip/hip_runtime.h>
#include <float.h>

// Model constants: N=20000, E=320000, F_IN=256, HID=32, HEADS=8, EDGE_DIM=8

typedef short v8s __attribute__((ext_vector_type(8)));
typedef float v4f __attribute__((ext_vector_type(4)));

__device__ __forceinline__ ushort f2bf(float f) {
  unsigned u = __float_as_uint(f);
  u = (u + 0x7FFF + ((u >> 16) & 1)) >> 16;
  return (ushort)u;
}
__device__ __forceinline__ float bf2f(ushort h) {
  return __uint_as_float(((unsigned)h) << 16);
}

// ---------------------------------------------------------------- CSR build
// Exclusive prefix sum of deg (real edges only; self-loops handled in-conv).
__global__ __launch_bounds__(1024) void k_scan(const int* __restrict__ deg,
                                               int* __restrict__ row_ptr, int N) {
  __shared__ int part[1024];
  int tid = threadIdx.x;
  int chunk = (N + 1023) / 1024;
  int lo = tid * chunk;
  if (lo > N) lo = N;
  int hi = lo + chunk;
  if (hi > N) hi = N;
  int s = 0;
  for (int i = lo; i < hi; i++) s += deg[i];
  part[tid] = s;
  __syncthreads();
  for (int off = 1; off < 1024; off <<= 1) {
    int v = 0;
    if (tid >= off) v = part[tid - off];
    __syncthreads();
    part[tid] += v;
    __syncthreads();
  }
  int base = part[tid] - s;  // exclusive prefix
  for (int i = lo; i < hi; i++) { row_ptr[i] = base; base += deg[i]; }
  if (tid == 1023) row_ptr[N] = part[1023];
}

// Scatter real edges into CSR order by dst; aed payload carried along so the
// conv kernels read it contiguously.
__global__ void k_scatter(const int* __restrict__ src, const int* __restrict__ dst,
                          const int* __restrict__ row_ptr, int* __restrict__ cursor,
                          const float* __restrict__ aed1_lin, const float* __restrict__ aed2_lin,
                          int* __restrict__ csr_src, float* __restrict__ csr_aed1,
                          float* __restrict__ csr_aed2, int E) {
  int i = blockIdx.x * blockDim.x + threadIdx.x;
  if (i >= E) return;
  int d = dst[i];
  int pos = row_ptr[d] + atomicAdd(&cursor[d], 1);
  csr_src[pos] = src[i];
  const float4* a4 = (const float4*)(aed1_lin + (size_t)i * 8);
  *(float4*)(csr_aed1 + (size_t)pos * 8)     = a4[0];
  *(float4*)(csr_aed1 + (size_t)pos * 8 + 4) = a4[1];
  csr_aed2[pos] = aed2_lin[i];
}

// ------------------------------------- prep (block 64) + W1 transpose (blocks 0-63)
__global__ __launch_bounds__(256) void k_prep_trans(const float* __restrict__ W1,
                                                    const float* __restrict__ We1,
                                                    const float* __restrict__ ae1,
                                                    const float* __restrict__ We2,
                                                    const float* __restrict__ ae2,
                                                    ushort* __restrict__ Bt,
                                                    float* __restrict__ M1,
                                                    float* __restrict__ m2) {
  if (blockIdx.x == 64) {
    int t = threadIdx.x;
    if (t < 64) {
      int k = t >> 3, h = t & 7;
      float s = 0.f;
      for (int c = 0; c < 32; c++) s += We1[k * 256 + h * 32 + c] * ae1[h * 32 + c];
      M1[k * 8 + h] = s;
    } else if (t < 72) {
      int k = t - 64;
      float s = 0.f;
      for (int c = 0; c < 32; c++) s += We2[k * 32 + c] * ae2[c];
      m2[k] = s;
    }
    return;
  }
  __shared__ float tile[32][33];
  int bx = blockIdx.x & 7, by = blockIdx.x >> 3;
  int tx = threadIdx.x & 31, ty = threadIdx.x >> 5;
  for (int r = ty; r < 32; r += 8)
    tile[r][tx] = W1[(size_t)(by * 32 + r) * 256 + bx * 32 + tx];
  __syncthreads();
  for (int r = ty; r < 32; r += 8)
    Bt[(size_t)(bx * 32 + r) * 256 + by * 32 + tx] = f2bf(tile[tx][r]);
}

// ------------------------------- fused edge logits + degree count (one pass)
__global__ void k_edge_fused(const float* __restrict__ ea, const int* __restrict__ dst,
                             const float* __restrict__ Wse, const float* __restrict__ bse,
                             const float* __restrict__ M1, const float* __restrict__ m2,
                             float* __restrict__ aed1, float* __restrict__ aed2,
                             int* __restrict__ deg, int E) {
  __shared__ float sW[16], sb[8], sM[64], sm2[8];
  int t = threadIdx.x;
  if (t < 16) sW[t] = Wse[t];
  if (t < 8) sb[t] = bse[t];
  if (t < 64) sM[t] = M1[t];
  if (t >= 64 && t < 72) sm2[t - 64] = m2[t - 64];
  __syncthreads();
  int e = blockIdx.x * blockDim.x + t;
  if (e >= E) return;
  atomicAdd(&deg[dst[e]], 1);
  float2 av = ((const float2*)ea)[e];
  float e8[8];
#pragma unroll
  for (int k = 0; k < 8; k++)
    e8[k] = fmaxf(av.x * sW[k] + av.y * sW[8 + k] + sb[k], 0.f);
  float o[8];
#pragma unroll
  for (int h = 0; h < 8; h++) {
    float s = 0.f;
#pragma unroll
    for (int k = 0; k < 8; k++) s += e8[k] * sM[k * 8 + h];
    o[h] = s;
  }
  *(float4*)(aed1 + (size_t)e * 8)     = make_float4(o[0], o[1], o[2], o[3]);
  *(float4*)(aed1 + (size_t)e * 8 + 4) = make_float4(o[4], o[5], o[6], o[7]);
  float s2 = 0.f;
#pragma unroll
  for (int k = 0; k < 8; k++) s2 += e8[k] * sm2[k];
  aed2[e] = s2;
}

// ---------------------------------------------------------------- GEMM1 (MFMA bf16)
// h1b = bf16(x @ W1); fused attn1 epilogue.
__global__ __launch_bounds__(256) void k_gemm1_mfma(const float* __restrict__ A,
                                                    const ushort* __restrict__ Bt,
                                                    const float* __restrict__ as1,
                                                    const float* __restrict__ ad1,
                                                    ushort* __restrict__ h1b,
                                                    float* __restrict__ asv,
                                                    float* __restrict__ adv, int M) {
  __shared__ ushort sA[64 * 40];   // [row][k] bf16, stride 40
  __shared__ ushort sB[256 * 40];  // [col][k] bf16, stride 40
  __shared__ float sas[256], sad[256];
  int t = threadIdx.x;
  int wave = t >> 6, lane = t & 63;
  int m0 = blockIdx.x * 64;
  int c = lane & 15, kg = lane >> 4;
  sas[t] = as1[t];
  sad[t] = ad1[t];
  v4f acc[4][4];
#pragma unroll
  for (int a = 0; a < 4; a++)
#pragma unroll
    for (int b = 0; b < 4; b++) acc[a][b] = (v4f)(0.f);
  int arow = t >> 2;
  int akoff = (t & 3) * 8;
  bool aval = (m0 + arow) < M;
  const float* aptr = A + (size_t)(m0 + arow) * 256 + akoff;
  const ushort* bptr = Bt + (size_t)t * 256;
  for (int k0 = 0; k0 < 256; k0 += 32) {
    float4 v0 = make_float4(0.f, 0.f, 0.f, 0.f), v1 = v0;
    if (aval) { v0 = *(const float4*)(aptr + k0); v1 = *(const float4*)(aptr + k0 + 4); }
    ushort* dst = &sA[arow * 40 + akoff];
    dst[0] = f2bf(v0.x); dst[1] = f2bf(v0.y); dst[2] = f2bf(v0.z); dst[3] = f2bf(v0.w);
    dst[4] = f2bf(v1.x); dst[5] = f2bf(v1.y); dst[6] = f2bf(v1.z); dst[7] = f2bf(v1.w);
    *(v8s*)&sB[t * 40 + 0]  = *(const v8s*)(bptr + k0 + 0);
    *(v8s*)&sB[t * 40 + 8]  = *(const v8s*)(bptr + k0 + 8);
    *(v8s*)&sB[t * 40 + 16] = *(const v8s*)(bptr + k0 + 16);
    *(v8s*)&sB[t * 40 + 24] = *(const v8s*)(bptr + k0 + 24);
    __syncthreads();
    v8s af[4], bfr[4];
#pragma unroll
    for (int mt = 0; mt < 4; mt++) af[mt] = *(v8s*)&sA[(mt * 16 + c) * 40 + kg * 8];
#pragma unroll
    for (int nt = 0; nt < 4; nt++) bfr[nt] = *(v8s*)&sB[(wave * 64 + nt * 16 + c) * 40 + kg * 8];
#pragma unroll
    for (int mt = 0; mt < 4; mt++)
#pragma unroll
      for (int nt = 0; nt < 4; nt++)
        acc[mt][nt] = __builtin_amdgcn_mfma_f32_16x16x32_bf16(af[mt], bfr[nt], acc[mt][nt], 0, 0, 0);
    __syncthreads();
  }
  // C/D layout: col = lane&15 (=c), row = kg*4 + reg
  int colbase = wave * 64;
#pragma unroll
  for (int mt = 0; mt < 4; mt++) {
#pragma unroll
    for (int i = 0; i < 4; i++) {
      int m = m0 + mt * 16 + kg * 4 + i;
      if (m < M) {
#pragma unroll
        for (int nt = 0; nt < 4; nt++)
          h1b[(size_t)m * 256 + colbase + nt * 16 + c] = f2bf(acc[mt][nt][i]);
      }
      float s1a = acc[mt][0][i] * sas[colbase + c]      + acc[mt][1][i] * sas[colbase + 16 + c];
      float s2a = acc[mt][0][i] * sad[colbase + c]      + acc[mt][1][i] * sad[colbase + 16 + c];
      float s1b = acc[mt][2][i] * sas[colbase + 32 + c] + acc[mt][3][i] * sas[colbase + 48 + c];
      float s2b = acc[mt][2][i] * sad[colbase + 32 + c] + acc[mt][3][i] * sad[colbase + 48 + c];
#pragma unroll
      for (int o = 1; o < 16; o <<= 1) {
        s1a += __shfl_xor(s1a, o);
        s2a += __shfl_xor(s2a, o);
        s1b += __shfl_xor(s1b, o);
        s2b += __shfl_xor(s2b, o);
      }
      if (c == 0 && m < M) {
        asv[(size_t)m * 8 + 2 * wave]     = s1a;
        adv[(size_t)m * 8 + 2 * wave]     = s2a;
        asv[(size_t)m * 8 + 2 * wave + 1] = s1b;
        adv[(size_t)m * 8 + 2 * wave + 1] = s2b;
      }
    }
  }
}

// ------------------------------------------------- conv1: one wave per node (LDS-staged)
// Online softmax over real in-edges, then one merged self-loop step whose edge
// logit is the mean of the row's aed logits (PyG fill_value='mean' folded in).
__global__ __launch_bounds__(64) void k_conv1(
    const int* __restrict__ row_ptr, const int* __restrict__ csr_src,
    const float* __restrict__ csr_aed1, const float* __restrict__ asv,
    const float* __restrict__ adv, const ushort* __restrict__ h1b,
    const float* __restrict__ b1, ushort* __restrict__ h2b, int N) {
  int n = blockIdx.x;
  int lane = threadIdx.x;
  int h = lane >> 3;       // head owned in accumulate phase
  int sub = lane & 7;
  int hh = lane & 7;       // head owned in logit phase (idx & 7 stays lane&7)
  __shared__ float sw[64 * 8];
  __shared__ int ssrc[64];
  __shared__ float sm[8], sl[8], sadv[8], smean[8];
  int begin = row_ptr[n], end = row_ptr[n + 1];
  int degr = end - begin;
  if (lane < 8) { sm[lane] = -FLT_MAX; sl[lane] = 0.f; sadv[lane] = adv[(size_t)n * 8 + lane]; }
  float aedsum = 0.f;
  float4 acc = make_float4(0.f, 0.f, 0.f, 0.f);
  for (int cs = begin; cs < end; cs += 64) {
    int c = min(64, end - cs);
    __syncthreads();
    if (lane < c) ssrc[lane] = csr_src[cs + lane];
    __syncthreads();
    for (int idx = lane; idx < c * 8; idx += 64) {
      int el = idx >> 3;
      float ae = csr_aed1[(size_t)(cs + el) * 8 + hh];
      aedsum += ae;
      float a = asv[(size_t)ssrc[el] * 8 + hh] + sadv[hh] + ae;
      a = a > 0.f ? a : 0.2f * a;
      sw[idx] = a;
    }
    __syncthreads();
    float mloc = -FLT_MAX;
    for (int el = sub; el < c; el += 8) mloc = fmaxf(mloc, sw[el * 8 + h]);
#pragma unroll
    for (int o = 1; o < 8; o <<= 1) mloc = fmaxf(mloc, __shfl_xor(mloc, o));
    float mold = sm[h];
    float mnew = fmaxf(mold, mloc);
    float scale = __expf(mold - mnew);
    float lloc = 0.f;
    for (int el = sub; el < c; el += 8) {
      float w = __expf(sw[el * 8 + h] - mnew);
      sw[el * 8 + h] = w;
      lloc += w;
    }
#pragma unroll
    for (int o = 1; o < 8; o <<= 1) lloc += __shfl_xor(lloc, o);
    __syncthreads();
    if (sub == 0) { sm[h] = mnew; sl[h] = sl[h] * scale + lloc; }
    acc.x *= scale; acc.y *= scale; acc.z *= scale; acc.w *= scale;
    for (int el = 0; el < c; el++) {
      float w = sw[el * 8 + h];
      ushort4 hv = *(const ushort4*)(h1b + (size_t)ssrc[el] * 256 + lane * 4);
      acc.x += w * bf2f(hv.x);
      acc.y += w * bf2f(hv.y);
      acc.z += w * bf2f(hv.z);
      acc.w += w * bf2f(hv.w);
    }
  }
  // per-head aed mean: reduce over lanes with equal (lane&7)
  aedsum += __shfl_xor(aedsum, 8);
  aedsum += __shfl_xor(aedsum, 16);
  aedsum += __shfl_xor(aedsum, 32);
  float invd = 1.f / (float)(degr > 1 ? degr : 1);
  if (lane < 8) smean[lane] = aedsum * invd;
  __syncthreads();
  // merged self-loop step (head h)
  float a_self = asv[(size_t)n * 8 + h] + sadv[h] + smean[h];
  a_self = a_self > 0.f ? a_self : 0.2f * a_self;
  float mold = sm[h];
  float mnew = fmaxf(mold, a_self);
  float scale = __expf(mold - mnew);
  float w_self = __expf(a_self - mnew);
  float l_fin = sl[h] * scale + w_self;
  ushort4 hs = *(const ushort4*)(h1b + (size_t)n * 256 + lane * 4);
  acc.x = acc.x * scale + w_self * bf2f(hs.x);
  acc.y = acc.y * scale + w_self * bf2f(hs.y);
  acc.z = acc.z * scale + w_self * bf2f(hs.z);
  acc.w = acc.w * scale + w_self * bf2f(hs.w);
  float inv = 1.f / (l_fin + 1e-16f);
  float4 bv = *(const float4*)(b1 + lane * 4);
  ushort4 o4;
  o4.x = f2bf(fmaxf(acc.x * inv + bv.x, 0.f));
  o4.y = f2bf(fmaxf(acc.y * inv + bv.y, 0.f));
  o4.z = f2bf(fmaxf(acc.z * inv + bv.z, 0.f));
  o4.w = f2bf(fmaxf(acc.w * inv + bv.w, 0.f));
  *(ushort4*)(h2b + (size_t)n * 256 + lane * 4) = o4;
}

// g2 = h2 @ W2 (256 -> 32), 8 nodes/block; fused asv2/adv2 epilogue.
__global__ __launch_bounds__(256) void k_gemm2(const ushort* __restrict__ h2b,
                                               const float* __restrict__ W2,
                                               const float* __restrict__ as2,
                                               const float* __restrict__ ad2,
                                               float* __restrict__ g2,
                                               float* __restrict__ asv2,
                                               float* __restrict__ adv2, int N) {
  __shared__ float xs[8 * 256];
  __shared__ float sas[32], sad[32];
  int t = threadIdx.x;
  if (t < 32) { sas[t] = as2[t]; sad[t] = ad2[t]; }
  int n0 = blockIdx.x * 8;
  for (int idx = t; idx < 8 * 256; idx += 256) {
    int node = n0 + (idx >> 8);
    xs[idx] = (node < N) ? bf2f(h2b[(size_t)node * 256 + (idx & 255)]) : 0.f;
  }
  __syncthreads();
  int j = t >> 5, cc = t & 31;
  int node = n0 + j;
  float acc = 0.f;
#pragma unroll 8
  for (int k = 0; k < 256; k++) acc += xs[j * 256 + k] * W2[k * 32 + cc];
  float s1 = acc * sas[cc], s2 = acc * sad[cc];
#pragma unroll
  for (int o = 1; o < 32; o <<= 1) {
    s1 += __shfl_xor(s1, o);
    s2 += __shfl_xor(s2, o);
  }
  if (node < N) {
    g2[(size_t)node * 32 + cc] = acc;
    if (cc == 0) { asv2[node] = s1; adv2[node] = s2; }
  }
}

// ------------------------------------------------- conv2: one wave per node (LDS-staged)
// Same merged self-loop trick, single head.
__global__ __launch_bounds__(64) void k_conv2(
    const int* __restrict__ row_ptr, const int* __restrict__ csr_src,
    const float* __restrict__ csr_aed2, const float* __restrict__ asv2,
    const float* __restrict__ adv2, const float* __restrict__ g2,
    const float* __restrict__ b2, float* __restrict__ out, int N) {
  int n = blockIdx.x;
  int lane = threadIdx.x;
  int sub = lane >> 3, q = lane & 7;
  __shared__ float sw[64];
  __shared__ int ssrc[64];
  int begin = row_ptr[n], end = row_ptr[n + 1];
  int degr = end - begin;
  float advn = adv2[n];
  float m = -FLT_MAX, l = 0.f, aedsum = 0.f;
  float4 acc = make_float4(0.f, 0.f, 0.f, 0.f);
  for (int cs = begin; cs < end; cs += 64) {
    int c = min(64, end - cs);
    __syncthreads();
    float a = -FLT_MAX;
    if (lane < c) {
      int s = csr_src[cs + lane];
      ssrc[lane] = s;
      float ae = csr_aed2[cs + lane];
      aedsum += ae;
      a = asv2[s] + advn + ae;
      a = a > 0.f ? a : 0.2f * a;
    }
    float cm = a;
#pragma unroll
    for (int o = 1; o < 64; o <<= 1) cm = fmaxf(cm, __shfl_xor(cm, o));
    float nm = fmaxf(m, cm);
    float sc = __expf(m - nm);
    float w = (lane < c) ? __expf(a - nm) : 0.f;
    float cl = w;
#pragma unroll
    for (int o = 1; o < 64; o <<= 1) cl += __shfl_xor(cl, o);
    l = l * sc + cl;
    m = nm;
    sw[lane] = w;
    __syncthreads();
    acc.x *= sc; acc.y *= sc; acc.z *= sc; acc.w *= sc;
    for (int el = sub; el < c; el += 8) {
      float w2 = sw[el];
      const float4 gv = *(const float4*)(g2 + (size_t)ssrc[el] * 32 + q * 4);
      acc.x += w2 * gv.x; acc.y += w2 * gv.y; acc.z += w2 * gv.z; acc.w += w2 * gv.w;
    }
  }
  // self-loop merge
#pragma unroll
  for (int o = 1; o < 64; o <<= 1) aedsum += __shfl_xor(aedsum, o);
  float invd = 1.f / (float)(degr > 1 ? degr : 1);
  float a_self = asv2[n] + advn + aedsum * invd;
  a_self = a_self > 0.f ? a_self : 0.2f * a_self;
  float nm = fmaxf(m, a_self);
  float sc = __expf(m - nm);
  float w_self = __expf(a_self - nm);
  l = l * sc + w_self;
  acc.x *= sc; acc.y *= sc; acc.z *= sc; acc.w *= sc;
  if (sub == 0) {  // one subgroup adds the self message (covers all 32 channels)
    const float4 gv = *(const float4*)(g2 + (size_t)n * 32 + q * 4);
    acc.x += w_self * gv.x; acc.y += w_self * gv.y;
    acc.z += w_self * gv.z; acc.w += w_self * gv.w;
  }
#pragma unroll
  for (int o = 8; o < 64; o <<= 1) {
    acc.x += __shfl_xor(acc.x, o);
    acc.y += __shfl_xor(acc.y, o);
    acc.z += __shfl_xor(acc.z, o);
    acc.w += __shfl_xor(acc.w, o);
  }
  if (lane < 8) {
    float inv = 1.f / (l + 1e-16f);
    float4 bv = *(const float4*)(b2 + lane * 4);
    float4 o4;
    o4.x = acc.x * inv + bv.x;
    o4.y = acc.y * inv + bv.y;
    o4.z = acc.z * inv + bv.z;
    o4.w = acc.w * inv + bv.w;
    *(float4*)(out + (size_t)n * 32 + lane * 4) = o4;
  }
}

// ---------------------------------------------------------------- launch
extern "C" void kernel_launch(void* const* d_in, const int* in_sizes, int n_in,
                              void* d_out, int out_size, void* d_ws, size_t ws_size,
                              hipStream_t stream) {
  (void)n_in; (void)out_size; (void)ws_size;
  const float* x   = (const float*)d_in[0];
  const int*   ei  = (const int*)d_in[1];
  const float* ea  = (const float*)d_in[2];
  const float* Wse = (const float*)d_in[3];
  const float* bse = (const float*)d_in[4];
  const float* W1  = (const float*)d_in[5];
  const float* as1 = (const float*)d_in[6];
  const float* ad1 = (const float*)d_in[7];
  const float* We1 = (const float*)d_in[8];
  const float* ae1 = (const float*)d_in[9];
  const float* b1  = (const float*)d_in[10];
  const float* W2  = (const float*)d_in[11];
  const float* as2 = (const float*)d_in[12];
  const float* ad2 = (const float*)d_in[13];
  const float* We2 = (const float*)d_in[14];
  const float* ae2 = (const float*)d_in[15];
  const float* b2  = (const float*)d_in[16];
  const int N = in_sizes[0] / 256;
  const int E = in_sizes[1] / 2;
  const int* src = ei;
  const int* dst = ei + E;

  char* base = (char*)d_ws;
  size_t off = 0;
  auto alloc = [&](size_t bytes) -> char* {
    off = (off + 255) & ~(size_t)255;
    char* p = base + off;
    off += bytes;
    return p;
  };
  int*   deg      = (int*)alloc((size_t)N * 4);
  int*   cursor   = (int*)alloc((size_t)N * 4);
  size_t zero_bytes = (size_t)((char*)(cursor + N) - (char*)deg);
  int* row_ptr    = (int*)alloc((size_t)(N + 1) * 4);
  int* csr_src    = (int*)alloc((size_t)E * 4);
  float* aed1_lin = (float*)alloc((size_t)E * 8 * 4);
  float* aed2_lin = (float*)alloc((size_t)E * 4);
  float* csr_aed1 = (float*)alloc((size_t)E * 8 * 4);
  float* csr_aed2 = (float*)alloc((size_t)E * 4);
  ushort* W1T     = (ushort*)alloc((size_t)256 * 256 * 2);
  ushort* h1b     = (ushort*)alloc((size_t)N * 256 * 2);
  float* asv1     = (float*)alloc((size_t)N * 8 * 4);
  float* adv1     = (float*)alloc((size_t)N * 8 * 4);
  ushort* h2b     = (ushort*)alloc((size_t)N * 256 * 2);
  float* g2       = (float*)alloc((size_t)N * 32 * 4);
  float* asv2     = (float*)alloc((size_t)N * 4);
  float* adv2     = (float*)alloc((size_t)N * 4);
  float* M1       = (float*)alloc(64 * 4);
  float* m2       = (float*)alloc(8 * 4);

  hipMemsetAsync(deg, 0, zero_bytes, stream);
  k_prep_trans<<<65, 256, 0, stream>>>(W1, We1, ae1, We2, ae2, W1T, M1, m2);
  k_edge_fused<<<(E + 255) / 256, 256, 0, stream>>>(ea, dst, Wse, bse, M1, m2,
                                                    aed1_lin, aed2_lin, deg, E);
  k_scan<<<1, 1024, 0, stream>>>(deg, row_ptr, N);
  k_scatter<<<(E + 255) / 256, 256, 0, stream>>>(src, dst, row_ptr, cursor,
                                                 aed1_lin, aed2_lin,
                                                 csr_src, csr_aed1, csr_aed2, E);
  k_gemm1_mfma<<<(N + 63) / 64, 256, 0, stream>>>(x, W1T, as1, ad1, h1b, asv1, adv1, N);
  k_conv1<<<N, 64, 0, stream>>>(row_ptr, csr_src, csr_aed1, asv1, adv1, h1b, b1, h2b, N);
  k_gemm2<<<(N + 7) / 8, 256, 0, stream>>>(h2b, W2, as2, ad2, g2, asv2, adv2, N);
  k_conv2<<<N, 64, 0, stream>>>(row_ptr, csr_src, csr_aed2, asv2, adv2, g2, b2,
                                (float*)d_out, N);
}

// Round 9
// 257.010 us; speedup vs baseline: 1.0779x; 1.0052x over previous
//
#include <hip/hip_runtime.h>
#include <hip/hip_bf16.h>
#include <float.h>

// Model constants: N=20000, E=320000, F_IN=256, HID=32, HEADS=8, EDGE_DIM=8

typedef short v8s __attribute__((ext_vector_type(8)));
typedef float v4f __attribute__((ext_vector_type(4)));

__device__ __forceinline__ ushort f2bf(float f) {
  unsigned u = __float_as_uint(f);
  u = (u + 0x7FFF + ((u >> 16) & 1)) >> 16;
  return (ushort)u;
}
__device__ __forceinline__ float bf2f(ushort h) {
  return __uint_as_float(((unsigned)h) << 16);
}
__device__ __forceinline__ unsigned pk2bf(float lo, float hi) {
  return (unsigned)f2bf(lo) | ((unsigned)f2bf(hi) << 16);
}

// ------------------------- k_pre: deg count + W1 transpose + M1/m2 prep (fused)
// blocks [0, DB): degree count; [DB, DB+64): W1->W1T bf16 transpose; DB+64: prep.
__global__ __launch_bounds__(256) void k_pre(const int* __restrict__ dst,
                                             const float* __restrict__ W1,
                                             const float* __restrict__ We1,
                                             const float* __restrict__ ae1,
                                             const float* __restrict__ We2,
                                             const float* __restrict__ ae2,
                                             int* __restrict__ deg,
                                             ushort* __restrict__ Bt,
                                             float* __restrict__ M1,
                                             float* __restrict__ m2,
                                             int E, int DB) {
  int b = blockIdx.x;
  if (b < DB) {
    int e = b * 256 + threadIdx.x;
    if (e < E) atomicAdd(&deg[dst[e]], 1);
    return;
  }
  if (b == DB + 64) {
    int t = threadIdx.x;
    if (t < 64) {
      int k = t >> 3, h = t & 7;
      float s = 0.f;
      for (int c = 0; c < 32; c++) s += We1[k * 256 + h * 32 + c] * ae1[h * 32 + c];
      M1[k * 8 + h] = s;
    } else if (t < 72) {
      int k = t - 64;
      float s = 0.f;
      for (int c = 0; c < 32; c++) s += We2[k * 32 + c] * ae2[c];
      m2[k] = s;
    }
    return;
  }
  int b2 = b - DB;
  __shared__ float tile[32][33];
  int bx = b2 & 7, by = b2 >> 3;
  int tx = threadIdx.x & 31, ty = threadIdx.x >> 5;
  for (int r = ty; r < 32; r += 8)
    tile[r][tx] = W1[(size_t)(by * 32 + r) * 256 + bx * 32 + tx];
  __syncthreads();
  for (int r = ty; r < 32; r += 8)
    Bt[(size_t)(bx * 32 + r) * 256 + by * 32 + tx] = f2bf(tile[tx][r]);
}

// ---------------------------------------------------------------- CSR build
// Exclusive prefix sum of deg (real edges only; self-loops folded into convs).
__global__ __launch_bounds__(1024) void k_scan(const int* __restrict__ deg,
                                               int* __restrict__ row_ptr, int N) {
  __shared__ int part[1024];
  int tid = threadIdx.x;
  int chunk = (N + 1023) / 1024;
  int lo = tid * chunk;
  if (lo > N) lo = N;
  int hi = lo + chunk;
  if (hi > N) hi = N;
  int s = 0;
  for (int i = lo; i < hi; i++) s += deg[i];
  part[tid] = s;
  __syncthreads();
  for (int off = 1; off < 1024; off <<= 1) {
    int v = 0;
    if (tid >= off) v = part[tid - off];
    __syncthreads();
    part[tid] += v;
    __syncthreads();
  }
  int base = part[tid] - s;  // exclusive prefix
  for (int i = lo; i < hi; i++) { row_ptr[i] = base; base += deg[i]; }
  if (tid == 1023) row_ptr[N] = part[1023];
}

// -------------------- scatter with inline edge-logit computation (no lin arrays)
__global__ void k_scatter(const int* __restrict__ src, const int* __restrict__ dst,
                          const float* __restrict__ ea,
                          const float* __restrict__ Wse, const float* __restrict__ bse,
                          const float* __restrict__ M1, const float* __restrict__ m2,
                          const int* __restrict__ row_ptr, int* __restrict__ cursor,
                          int* __restrict__ csr_src, float* __restrict__ csr_aed1,
                          float* __restrict__ csr_aed2, int E) {
  __shared__ float sW[16], sb[8], sM[64], sm2[8];
  int t = threadIdx.x;
  if (t < 16) sW[t] = Wse[t];
  if (t < 8) sb[t] = bse[t];
  if (t < 64) sM[t] = M1[t];
  if (t >= 64 && t < 72) sm2[t - 64] = m2[t - 64];
  __syncthreads();
  int i = blockIdx.x * blockDim.x + t;
  if (i >= E) return;
  float2 av = ((const float2*)ea)[i];
  float e8[8];
#pragma unroll
  for (int k = 0; k < 8; k++)
    e8[k] = fmaxf(av.x * sW[k] + av.y * sW[8 + k] + sb[k], 0.f);
  float o[8];
#pragma unroll
  for (int h = 0; h < 8; h++) {
    float s = 0.f;
#pragma unroll
    for (int k = 0; k < 8; k++) s += e8[k] * sM[k * 8 + h];
    o[h] = s;
  }
  float s2 = 0.f;
#pragma unroll
  for (int k = 0; k < 8; k++) s2 += e8[k] * sm2[k];
  int d = dst[i];
  int pos = row_ptr[d] + atomicAdd(&cursor[d], 1);
  csr_src[pos] = src[i];
  *(float4*)(csr_aed1 + (size_t)pos * 8)     = make_float4(o[0], o[1], o[2], o[3]);
  *(float4*)(csr_aed1 + (size_t)pos * 8 + 4) = make_float4(o[4], o[5], o[6], o[7]);
  csr_aed2[pos] = s2;
}

// ---------------------------------------------------------------- GEMM1 (MFMA bf16)
// h1b = bf16(x @ W1); fused attn1 epilogue.
__global__ __launch_bounds__(256) void k_gemm1_mfma(const float* __restrict__ A,
                                                    const ushort* __restrict__ Bt,
                                                    const float* __restrict__ as1,
                                                    const float* __restrict__ ad1,
                                                    ushort* __restrict__ h1b,
                                                    float* __restrict__ asv,
                                                    float* __restrict__ adv, int M) {
  __shared__ ushort sA[64 * 40];   // [row][k] bf16, stride 40
  __shared__ ushort sB[256 * 40];  // [col][k] bf16, stride 40
  __shared__ float sas[256], sad[256];
  int t = threadIdx.x;
  int wave = t >> 6, lane = t & 63;
  int m0 = blockIdx.x * 64;
  int c = lane & 15, kg = lane >> 4;
  sas[t] = as1[t];
  sad[t] = ad1[t];
  v4f acc[4][4];
#pragma unroll
  for (int a = 0; a < 4; a++)
#pragma unroll
    for (int b = 0; b < 4; b++) acc[a][b] = (v4f)(0.f);
  int arow = t >> 2;
  int akoff = (t & 3) * 8;
  bool aval = (m0 + arow) < M;
  const float* aptr = A + (size_t)(m0 + arow) * 256 + akoff;
  const ushort* bptr = Bt + (size_t)t * 256;
  for (int k0 = 0; k0 < 256; k0 += 32) {
    float4 v0 = make_float4(0.f, 0.f, 0.f, 0.f), v1 = v0;
    if (aval) { v0 = *(const float4*)(aptr + k0); v1 = *(const float4*)(aptr + k0 + 4); }
    unsigned* dst32 = (unsigned*)&sA[arow * 40 + akoff];
    dst32[0] = pk2bf(v0.x, v0.y);
    dst32[1] = pk2bf(v0.z, v0.w);
    dst32[2] = pk2bf(v1.x, v1.y);
    dst32[3] = pk2bf(v1.z, v1.w);
    *(v8s*)&sB[t * 40 + 0]  = *(const v8s*)(bptr + k0 + 0);
    *(v8s*)&sB[t * 40 + 8]  = *(const v8s*)(bptr + k0 + 8);
    *(v8s*)&sB[t * 40 + 16] = *(const v8s*)(bptr + k0 + 16);
    *(v8s*)&sB[t * 40 + 24] = *(const v8s*)(bptr + k0 + 24);
    __syncthreads();
    v8s af[4], bfr[4];
#pragma unroll
    for (int mt = 0; mt < 4; mt++) af[mt] = *(v8s*)&sA[(mt * 16 + c) * 40 + kg * 8];
#pragma unroll
    for (int nt = 0; nt < 4; nt++) bfr[nt] = *(v8s*)&sB[(wave * 64 + nt * 16 + c) * 40 + kg * 8];
#pragma unroll
    for (int mt = 0; mt < 4; mt++)
#pragma unroll
      for (int nt = 0; nt < 4; nt++)
        acc[mt][nt] = __builtin_amdgcn_mfma_f32_16x16x32_bf16(af[mt], bfr[nt], acc[mt][nt], 0, 0, 0);
    __syncthreads();
  }
  // C/D layout: col = lane&15 (=c), row = kg*4 + reg
  int colbase = wave * 64;
#pragma unroll
  for (int mt = 0; mt < 4; mt++) {
#pragma unroll
    for (int i = 0; i < 4; i++) {
      int m = m0 + mt * 16 + kg * 4 + i;
      if (m < M) {
#pragma unroll
        for (int nt = 0; nt < 4; nt++)
          h1b[(size_t)m * 256 + colbase + nt * 16 + c] = f2bf(acc[mt][nt][i]);
      }
      float s1a = acc[mt][0][i] * sas[colbase + c]      + acc[mt][1][i] * sas[colbase + 16 + c];
      float s2a = acc[mt][0][i] * sad[colbase + c]      + acc[mt][1][i] * sad[colbase + 16 + c];
      float s1b = acc[mt][2][i] * sas[colbase + 32 + c] + acc[mt][3][i] * sas[colbase + 48 + c];
      float s2b = acc[mt][2][i] * sad[colbase + 32 + c] + acc[mt][3][i] * sad[colbase + 48 + c];
#pragma unroll
      for (int o = 1; o < 16; o <<= 1) {
        s1a += __shfl_xor(s1a, o);
        s2a += __shfl_xor(s2a, o);
        s1b += __shfl_xor(s1b, o);
        s2b += __shfl_xor(s2b, o);
      }
      if (c == 0 && m < M) {
        asv[(size_t)m * 8 + 2 * wave]     = s1a;
        adv[(size_t)m * 8 + 2 * wave]     = s2a;
        asv[(size_t)m * 8 + 2 * wave + 1] = s1b;
        adv[(size_t)m * 8 + 2 * wave + 1] = s2b;
      }
    }
  }
}

// ------------------------------------------------- conv1: one wave per node (LDS-staged)
// Online softmax over real in-edges, then one merged self-loop step whose edge
// logit is the mean of the row's aed logits (PyG fill_value='mean' folded in).
__global__ __launch_bounds__(64) void k_conv1(
    const int* __restrict__ row_ptr, const int* __restrict__ csr_src,
    const float* __restrict__ csr_aed1, const float* __restrict__ asv,
    const float* __restrict__ adv, const ushort* __restrict__ h1b,
    const float* __restrict__ b1, ushort* __restrict__ h2b, int N) {
  int n = blockIdx.x;
  int lane = threadIdx.x;
  int h = lane >> 3;       // head owned in accumulate phase
  int sub = lane & 7;
  int hh = lane & 7;       // head owned in logit phase
  __shared__ float sw[64 * 8];
  __shared__ int ssrc[64];
  __shared__ float sm[8], sl[8], sadv[8], smean[8];
  int begin = row_ptr[n], end = row_ptr[n + 1];
  int degr = end - begin;
  if (lane < 8) { sm[lane] = -FLT_MAX; sl[lane] = 0.f; sadv[lane] = adv[(size_t)n * 8 + lane]; }
  float aedsum = 0.f;
  float4 acc = make_float4(0.f, 0.f, 0.f, 0.f);
  for (int cs = begin; cs < end; cs += 64) {
    int c = min(64, end - cs);
    __syncthreads();
    if (lane < c) ssrc[lane] = csr_src[cs + lane];
    __syncthreads();
    for (int idx = lane; idx < c * 8; idx += 64) {
      int el = idx >> 3;
      float ae = csr_aed1[(size_t)(cs + el) * 8 + hh];
      aedsum += ae;
      float a = asv[(size_t)ssrc[el] * 8 + hh] + sadv[hh] + ae;
      a = a > 0.f ? a : 0.2f * a;
      sw[idx] = a;
    }
    __syncthreads();
    float mloc = -FLT_MAX;
    for (int el = sub; el < c; el += 8) mloc = fmaxf(mloc, sw[el * 8 + h]);
#pragma unroll
    for (int o = 1; o < 8; o <<= 1) mloc = fmaxf(mloc, __shfl_xor(mloc, o));
    float mold = sm[h];
    float mnew = fmaxf(mold, mloc);
    float scale = __expf(mold - mnew);
    float lloc = 0.f;
    for (int el = sub; el < c; el += 8) {
      float w = __expf(sw[el * 8 + h] - mnew);
      sw[el * 8 + h] = w;
      lloc += w;
    }
#pragma unroll
    for (int o = 1; o < 8; o <<= 1) lloc += __shfl_xor(lloc, o);
    __syncthreads();
    if (sub == 0) { sm[h] = mnew; sl[h] = sl[h] * scale + lloc; }
    acc.x *= scale; acc.y *= scale; acc.z *= scale; acc.w *= scale;
    for (int el = 0; el < c; el++) {
      float w = sw[el * 8 + h];
      ushort4 hv = *(const ushort4*)(h1b + (size_t)ssrc[el] * 256 + lane * 4);
      acc.x += w * bf2f(hv.x);
      acc.y += w * bf2f(hv.y);
      acc.z += w * bf2f(hv.z);
      acc.w += w * bf2f(hv.w);
    }
  }
  // per-head aed mean: reduce over lanes with equal (lane&7)
  aedsum += __shfl_xor(aedsum, 8);
  aedsum += __shfl_xor(aedsum, 16);
  aedsum += __shfl_xor(aedsum, 32);
  float invd = 1.f / (float)(degr > 1 ? degr : 1);
  if (lane < 8) smean[lane] = aedsum * invd;
  __syncthreads();
  // merged self-loop step (head h)
  float a_self = asv[(size_t)n * 8 + h] + sadv[h] + smean[h];
  a_self = a_self > 0.f ? a_self : 0.2f * a_self;
  float mold = sm[h];
  float mnew = fmaxf(mold, a_self);
  float scale = __expf(mold - mnew);
  float w_self = __expf(a_self - mnew);
  float l_fin = sl[h] * scale + w_self;
  ushort4 hs = *(const ushort4*)(h1b + (size_t)n * 256 + lane * 4);
  acc.x = acc.x * scale + w_self * bf2f(hs.x);
  acc.y = acc.y * scale + w_self * bf2f(hs.y);
  acc.z = acc.z * scale + w_self * bf2f(hs.z);
  acc.w = acc.w * scale + w_self * bf2f(hs.w);
  float inv = 1.f / (l_fin + 1e-16f);
  float4 bv = *(const float4*)(b1 + lane * 4);
  ushort4 o4;
  o4.x = f2bf(fmaxf(acc.x * inv + bv.x, 0.f));
  o4.y = f2bf(fmaxf(acc.y * inv + bv.y, 0.f));
  o4.z = f2bf(fmaxf(acc.z * inv + bv.z, 0.f));
  o4.w = f2bf(fmaxf(acc.w * inv + bv.w, 0.f));
  *(ushort4*)(h2b + (size_t)n * 256 + lane * 4) = o4;
}

// g2 = h2 @ W2 (256 -> 32), 8 nodes/block; fused asv2/adv2 epilogue.
__global__ __launch_bounds__(256) void k_gemm2(const ushort* __restrict__ h2b,
                                               const float* __restrict__ W2,
                                               const float* __restrict__ as2,
                                               const float* __restrict__ ad2,
                                               float* __restrict__ g2,
                                               float* __restrict__ asv2,
                                               float* __restrict__ adv2, int N) {
  __shared__ float xs[8 * 256];
  __shared__ float sas[32], sad[32];
  int t = threadIdx.x;
  if (t < 32) { sas[t] = as2[t]; sad[t] = ad2[t]; }
  int n0 = blockIdx.x * 8;
  for (int idx = t; idx < 8 * 256; idx += 256) {
    int node = n0 + (idx >> 8);
    xs[idx] = (node < N) ? bf2f(h2b[(size_t)node * 256 + (idx & 255)]) : 0.f;
  }
  __syncthreads();
  int j = t >> 5, cc = t & 31;
  int node = n0 + j;
  float acc = 0.f;
#pragma unroll 8
  for (int k = 0; k < 256; k++) acc += xs[j * 256 + k] * W2[k * 32 + cc];
  float s1 = acc * sas[cc], s2 = acc * sad[cc];
#pragma unroll
  for (int o = 1; o < 32; o <<= 1) {
    s1 += __shfl_xor(s1, o);
    s2 += __shfl_xor(s2, o);
  }
  if (node < N) {
    g2[(size_t)node * 32 + cc] = acc;
    if (cc == 0) { asv2[node] = s1; adv2[node] = s2; }
  }
}

// ------------------------------------------------- conv2: one wave per node (LDS-staged)
__global__ __launch_bounds__(64) void k_conv2(
    const int* __restrict__ row_ptr, const int* __restrict__ csr_src,
    const float* __restrict__ csr_aed2, const float* __restrict__ asv2,
    const float* __restrict__ adv2, const float* __restrict__ g2,
    const float* __restrict__ b2, float* __restrict__ out, int N) {
  int n = blockIdx.x;
  int lane = threadIdx.x;
  int sub = lane >> 3, q = lane & 7;
  __shared__ float sw[64];
  __shared__ int ssrc[64];
  int begin = row_ptr[n], end = row_ptr[n + 1];
  int degr = end - begin;
  float advn = adv2[n];
  float m = -FLT_MAX, l = 0.f, aedsum = 0.f;
  float4 acc = make_float4(0.f, 0.f, 0.f, 0.f);
  for (int cs = begin; cs < end; cs += 64) {
    int c = min(64, end - cs);
    __syncthreads();
    float a = -FLT_MAX;
    if (lane < c) {
      int s = csr_src[cs + lane];
      ssrc[lane] = s;
      float ae = csr_aed2[cs + lane];
      aedsum += ae;
      a = asv2[s] + advn + ae;
      a = a > 0.f ? a : 0.2f * a;
    }
    float cm = a;
#pragma unroll
    for (int o = 1; o < 64; o <<= 1) cm = fmaxf(cm, __shfl_xor(cm, o));
    float nm = fmaxf(m, cm);
    float sc = __expf(m - nm);
    float w = (lane < c) ? __expf(a - nm) : 0.f;
    float cl = w;
#pragma unroll
    for (int o = 1; o < 64; o <<= 1) cl += __shfl_xor(cl, o);
    l = l * sc + cl;
    m = nm;
    sw[lane] = w;
    __syncthreads();
    acc.x *= sc; acc.y *= sc; acc.z *= sc; acc.w *= sc;
    for (int el = sub; el < c; el += 8) {
      float w2 = sw[el];
      const float4 gv = *(const float4*)(g2 + (size_t)ssrc[el] * 32 + q * 4);
      acc.x += w2 * gv.x; acc.y += w2 * gv.y; acc.z += w2 * gv.z; acc.w += w2 * gv.w;
    }
  }
  // self-loop merge
#pragma unroll
  for (int o = 1; o < 64; o <<= 1) aedsum += __shfl_xor(aedsum, o);
  float invd = 1.f / (float)(degr > 1 ? degr : 1);
  float a_self = asv2[n] + advn + aedsum * invd;
  a_self = a_self > 0.f ? a_self : 0.2f * a_self;
  float nm = fmaxf(m, a_self);
  float sc = __expf(m - nm);
  float w_self = __expf(a_self - nm);
  l = l * sc + w_self;
  acc.x *= sc; acc.y *= sc; acc.z *= sc; acc.w *= sc;
  if (sub == 0) {  // one subgroup adds the self message (covers all 32 channels)
    const float4 gv = *(const float4*)(g2 + (size_t)n * 32 + q * 4);
    acc.x += w_self * gv.x; acc.y += w_self * gv.y;
    acc.z += w_self * gv.z; acc.w += w_self * gv.w;
  }
#pragma unroll
  for (int o = 8; o < 64; o <<= 1) {
    acc.x += __shfl_xor(acc.x, o);
    acc.y += __shfl_xor(acc.y, o);
    acc.z += __shfl_xor(acc.z, o);
    acc.w += __shfl_xor(acc.w, o);
  }
  if (lane < 8) {
    float inv = 1.f / (l + 1e-16f);
    float4 bv = *(const float4*)(b2 + lane * 4);
    float4 o4;
    o4.x = acc.x * inv + bv.x;
    o4.y = acc.y * inv + bv.y;
    o4.z = acc.z * inv + bv.z;
    o4.w = acc.w * inv + bv.w;
    *(float4*)(out + (size_t)n * 32 + lane * 4) = o4;
  }
}

// ---------------------------------------------------------------- launch
extern "C" void kernel_launch(void* const* d_in, const int* in_sizes, int n_in,
                              void* d_out, int out_size, void* d_ws, size_t ws_size,
                              hipStream_t stream) {
  (void)n_in; (void)out_size; (void)ws_size;
  const float* x   = (const float*)d_in[0];
  const int*   ei  = (const int*)d_in[1];
  const float* ea  = (const float*)d_in[2];
  const float* Wse = (const float*)d_in[3];
  const float* bse = (const float*)d_in[4];
  const float* W1  = (const float*)d_in[5];
  const float* as1 = (const float*)d_in[6];
  const float* ad1 = (const float*)d_in[7];
  const float* We1 = (const float*)d_in[8];
  const float* ae1 = (const float*)d_in[9];
  const float* b1  = (const float*)d_in[10];
  const float* W2  = (const float*)d_in[11];
  const float* as2 = (const float*)d_in[12];
  const float* ad2 = (const float*)d_in[13];
  const float* We2 = (const float*)d_in[14];
  const float* ae2 = (const float*)d_in[15];
  const float* b2  = (const float*)d_in[16];
  const int N = in_sizes[0] / 256;
  const int E = in_sizes[1] / 2;
  const int* src = ei;
  const int* dst = ei + E;

  char* base = (char*)d_ws;
  size_t off = 0;
  auto alloc = [&](size_t bytes) -> char* {
    off = (off + 255) & ~(size_t)255;
    char* p = base + off;
    off += bytes;
    return p;
  };
  int*   deg      = (int*)alloc((size_t)N * 4);
  int*   cursor   = (int*)alloc((size_t)N * 4);
  size_t zero_bytes = (size_t)((char*)(cursor + N) - (char*)deg);
  int* row_ptr    = (int*)alloc((size_t)(N + 1) * 4);
  int* csr_src    = (int*)alloc((size_t)E * 4);
  float* csr_aed1 = (float*)alloc((size_t)E * 8 * 4);
  float* csr_aed2 = (float*)alloc((size_t)E * 4);
  ushort* W1T     = (ushort*)alloc((size_t)256 * 256 * 2);
  ushort* h1b     = (ushort*)alloc((size_t)N * 256 * 2);
  float* asv1     = (float*)alloc((size_t)N * 8 * 4);
  float* adv1     = (float*)alloc((size_t)N * 8 * 4);
  ushort* h2b     = (ushort*)alloc((size_t)N * 256 * 2);
  float* g2       = (float*)alloc((size_t)N * 32 * 4);
  float* asv2     = (float*)alloc((size_t)N * 4);
  float* adv2     = (float*)alloc((size_t)N * 4);
  float* M1       = (float*)alloc(64 * 4);
  float* m2       = (float*)alloc(8 * 4);

  const int DB = (E + 255) / 256;
  hipMemsetAsync(deg, 0, zero_bytes, stream);
  k_pre<<<DB + 65, 256, 0, stream>>>(dst, W1, We1, ae1, We2, ae2, deg, W1T, M1, m2, E, DB);
  k_scan<<<1, 1024, 0, stream>>>(deg, row_ptr, N);
  k_scatter<<<DB, 256, 0, stream>>>(src, dst, ea, Wse, bse, M1, m2, row_ptr, cursor,
                                    csr_src, csr_aed1, csr_aed2, E);
  k_gemm1_mfma<<<(N + 63) / 64, 256, 0, stream>>>(x, W1T, as1, ad1, h1b, asv1, adv1, N);
  k_conv1<<<N, 64, 0, stream>>>(row_ptr, csr_src, csr_aed1, asv1, adv1, h1b, b1, h2b, N);
  k_gemm2<<<(N + 7) / 8, 256, 0, stream>>>(h2b, W2, as2, ad2, g2, asv2, adv2, N);
  k_conv2<<<N, 64, 0, stream>>>(row_ptr, csr_src, csr_aed2, asv2, adv2, g2, b2,
                                (float*)d_out, N);
}

// Round 10
// 256.214 us; speedup vs baseline: 1.0813x; 1.0031x over previous
//
#include <hip/hip_runtime.h>
#include <hip/hip_bf16.h>
#include <hip/hip_fp16.h>
#include <float.h>

// Model constants: N=20000, E=320000, F_IN=256, HID=32, HEADS=8, EDGE_DIM=8
// Edge record (32 B): [0] src:int, [4..20) aed1: 8 x f16, [20] aed2: f32, [24..32) pad

typedef short v8s __attribute__((ext_vector_type(8)));
typedef float v4f __attribute__((ext_vector_type(4)));

__device__ __forceinline__ ushort f2bf(float f) {
  unsigned u = __float_as_uint(f);
  u = (u + 0x7FFF + ((u >> 16) & 1)) >> 16;
  return (ushort)u;
}
__device__ __forceinline__ float bf2f(ushort h) {
  return __uint_as_float(((unsigned)h) << 16);
}
__device__ __forceinline__ unsigned pk2bf(float lo, float hi) {
  return (unsigned)f2bf(lo) | ((unsigned)f2bf(hi) << 16);
}
__device__ __forceinline__ unsigned pk2h(float lo, float hi) {
  return (unsigned)__half_as_ushort(__float2half(lo)) |
         ((unsigned)__half_as_ushort(__float2half(hi)) << 16);
}

// ------------------------- k_pre: deg count + W1 transpose + M1/m2 prep (fused)
__global__ __launch_bounds__(256) void k_pre(const int* __restrict__ dst,
                                             const float* __restrict__ W1,
                                             const float* __restrict__ We1,
                                             const float* __restrict__ ae1,
                                             const float* __restrict__ We2,
                                             const float* __restrict__ ae2,
                                             int* __restrict__ deg,
                                             ushort* __restrict__ Bt,
                                             float* __restrict__ M1,
                                             float* __restrict__ m2,
                                             int E, int DB) {
  int b = blockIdx.x;
  if (b < DB) {
    int e = b * 256 + threadIdx.x;
    if (e < E) atomicAdd(&deg[dst[e]], 1);
    return;
  }
  if (b == DB + 64) {
    int t = threadIdx.x;
    if (t < 64) {
      int k = t >> 3, h = t & 7;
      float s = 0.f;
      for (int c = 0; c < 32; c++) s += We1[k * 256 + h * 32 + c] * ae1[h * 32 + c];
      M1[k * 8 + h] = s;
    } else if (t < 72) {
      int k = t - 64;
      float s = 0.f;
      for (int c = 0; c < 32; c++) s += We2[k * 32 + c] * ae2[c];
      m2[k] = s;
    }
    return;
  }
  int b2 = b - DB;
  __shared__ float tile[32][33];
  int bx = b2 & 7, by = b2 >> 3;
  int tx = threadIdx.x & 31, ty = threadIdx.x >> 5;
  for (int r = ty; r < 32; r += 8)
    tile[r][tx] = W1[(size_t)(by * 32 + r) * 256 + bx * 32 + tx];
  __syncthreads();
  for (int r = ty; r < 32; r += 8)
    Bt[(size_t)(bx * 32 + r) * 256 + by * 32 + tx] = f2bf(tile[tx][r]);
}

// ---------------------------------------------------------------- CSR build
// Exclusive prefix sum of deg; also zeroes cursor (saves half the memset).
__global__ __launch_bounds__(1024) void k_scan(const int* __restrict__ deg,
                                               int* __restrict__ row_ptr,
                                               int* __restrict__ cursor, int N) {
  __shared__ int part[1024];
  int tid = threadIdx.x;
  int chunk = (N + 1023) / 1024;
  int lo = tid * chunk;
  if (lo > N) lo = N;
  int hi = lo + chunk;
  if (hi > N) hi = N;
  int s = 0;
  for (int i = lo; i < hi; i++) { s += deg[i]; cursor[i] = 0; }
  part[tid] = s;
  __syncthreads();
  for (int off = 1; off < 1024; off <<= 1) {
    int v = 0;
    if (tid >= off) v = part[tid - off];
    __syncthreads();
    part[tid] += v;
    __syncthreads();
  }
  int base = part[tid] - s;  // exclusive prefix
  for (int i = lo; i < hi; i++) { row_ptr[i] = base; base += deg[i]; }
  if (tid == 1023) row_ptr[N] = part[1023];
}

// -------------------- scatter: inline edge logits, single 32 B record per edge
__global__ void k_scatter(const int* __restrict__ src, const int* __restrict__ dst,
                          const float* __restrict__ ea,
                          const float* __restrict__ Wse, const float* __restrict__ bse,
                          const float* __restrict__ M1, const float* __restrict__ m2,
                          const int* __restrict__ row_ptr, int* __restrict__ cursor,
                          char* __restrict__ rec, int E) {
  __shared__ float sW[16], sb[8], sM[64], sm2[8];
  int t = threadIdx.x;
  if (t < 16) sW[t] = Wse[t];
  if (t < 8) sb[t] = bse[t];
  if (t < 64) sM[t] = M1[t];
  if (t >= 64 && t < 72) sm2[t - 64] = m2[t - 64];
  __syncthreads();
  int i = blockIdx.x * blockDim.x + t;
  if (i >= E) return;
  float2 av = ((const float2*)ea)[i];
  float e8[8];
#pragma unroll
  for (int k = 0; k < 8; k++)
    e8[k] = fmaxf(av.x * sW[k] + av.y * sW[8 + k] + sb[k], 0.f);
  float o[8];
#pragma unroll
  for (int h = 0; h < 8; h++) {
    float s = 0.f;
#pragma unroll
    for (int k = 0; k < 8; k++) s += e8[k] * sM[k * 8 + h];
    o[h] = s;
  }
  float s2 = 0.f;
#pragma unroll
  for (int k = 0; k < 8; k++) s2 += e8[k] * sm2[k];
  int d = dst[i];
  int pos = row_ptr[d] + atomicAdd(&cursor[d], 1);
  uint4 w0, w1;
  w0.x = (unsigned)src[i];
  w0.y = pk2h(o[0], o[1]);
  w0.z = pk2h(o[2], o[3]);
  w0.w = pk2h(o[4], o[5]);
  w1.x = pk2h(o[6], o[7]);
  w1.y = __float_as_uint(s2);
  w1.z = 0; w1.w = 0;
  *(uint4*)(rec + (size_t)pos * 32)      = w0;
  *(uint4*)(rec + (size_t)pos * 32 + 16) = w1;
}

// ---------------------------------------------------------------- GEMM1 (MFMA bf16)
__global__ __launch_bounds__(256) void k_gemm1_mfma(const float* __restrict__ A,
                                                    const ushort* __restrict__ Bt,
                                                    const float* __restrict__ as1,
                                                    const float* __restrict__ ad1,
                                                    ushort* __restrict__ h1b,
                                                    float* __restrict__ asv,
                                                    float* __restrict__ adv, int M) {
  __shared__ ushort sA[64 * 40];   // [row][k] bf16, stride 40
  __shared__ ushort sB[256 * 40];  // [col][k] bf16, stride 40
  __shared__ float sas[256], sad[256];
  int t = threadIdx.x;
  int wave = t >> 6, lane = t & 63;
  int m0 = blockIdx.x * 64;
  int c = lane & 15, kg = lane >> 4;
  sas[t] = as1[t];
  sad[t] = ad1[t];
  v4f acc[4][4];
#pragma unroll
  for (int a = 0; a < 4; a++)
#pragma unroll
    for (int b = 0; b < 4; b++) acc[a][b] = (v4f)(0.f);
  int arow = t >> 2;
  int akoff = (t & 3) * 8;
  bool aval = (m0 + arow) < M;
  const float* aptr = A + (size_t)(m0 + arow) * 256 + akoff;
  const ushort* bptr = Bt + (size_t)t * 256;
  for (int k0 = 0; k0 < 256; k0 += 32) {
    float4 v0 = make_float4(0.f, 0.f, 0.f, 0.f), v1 = v0;
    if (aval) { v0 = *(const float4*)(aptr + k0); v1 = *(const float4*)(aptr + k0 + 4); }
    unsigned* dst32 = (unsigned*)&sA[arow * 40 + akoff];
    dst32[0] = pk2bf(v0.x, v0.y);
    dst32[1] = pk2bf(v0.z, v0.w);
    dst32[2] = pk2bf(v1.x, v1.y);
    dst32[3] = pk2bf(v1.z, v1.w);
    *(v8s*)&sB[t * 40 + 0]  = *(const v8s*)(bptr + k0 + 0);
    *(v8s*)&sB[t * 40 + 8]  = *(const v8s*)(bptr + k0 + 8);
    *(v8s*)&sB[t * 40 + 16] = *(const v8s*)(bptr + k0 + 16);
    *(v8s*)&sB[t * 40 + 24] = *(const v8s*)(bptr + k0 + 24);
    __syncthreads();
    v8s af[4], bfr[4];
#pragma unroll
    for (int mt = 0; mt < 4; mt++) af[mt] = *(v8s*)&sA[(mt * 16 + c) * 40 + kg * 8];
#pragma unroll
    for (int nt = 0; nt < 4; nt++) bfr[nt] = *(v8s*)&sB[(wave * 64 + nt * 16 + c) * 40 + kg * 8];
#pragma unroll
    for (int mt = 0; mt < 4; mt++)
#pragma unroll
      for (int nt = 0; nt < 4; nt++)
        acc[mt][nt] = __builtin_amdgcn_mfma_f32_16x16x32_bf16(af[mt], bfr[nt], acc[mt][nt], 0, 0, 0);
    __syncthreads();
  }
  int colbase = wave * 64;
#pragma unroll
  for (int mt = 0; mt < 4; mt++) {
#pragma unroll
    for (int i = 0; i < 4; i++) {
      int m = m0 + mt * 16 + kg * 4 + i;
      if (m < M) {
#pragma unroll
        for (int nt = 0; nt < 4; nt++)
          h1b[(size_t)m * 256 + colbase + nt * 16 + c] = f2bf(acc[mt][nt][i]);
      }
      float s1a = acc[mt][0][i] * sas[colbase + c]      + acc[mt][1][i] * sas[colbase + 16 + c];
      float s2a = acc[mt][0][i] * sad[colbase + c]      + acc[mt][1][i] * sad[colbase + 16 + c];
      float s1b = acc[mt][2][i] * sas[colbase + 32 + c] + acc[mt][3][i] * sas[colbase + 48 + c];
      float s2b = acc[mt][2][i] * sad[colbase + 32 + c] + acc[mt][3][i] * sad[colbase + 48 + c];
#pragma unroll
      for (int o = 1; o < 16; o <<= 1) {
        s1a += __shfl_xor(s1a, o);
        s2a += __shfl_xor(s2a, o);
        s1b += __shfl_xor(s1b, o);
        s2b += __shfl_xor(s2b, o);
      }
      if (c == 0 && m < M) {
        asv[(size_t)m * 8 + 2 * wave]     = s1a;
        adv[(size_t)m * 8 + 2 * wave]     = s2a;
        asv[(size_t)m * 8 + 2 * wave + 1] = s1b;
        adv[(size_t)m * 8 + 2 * wave + 1] = s2b;
      }
    }
  }
}

// ------------------------------------------------- conv1: one wave per node (LDS-staged)
__global__ __launch_bounds__(64) void k_conv1(
    const int* __restrict__ row_ptr, const char* __restrict__ rec,
    const float* __restrict__ asv, const float* __restrict__ adv,
    const ushort* __restrict__ h1b, const float* __restrict__ b1,
    ushort* __restrict__ h2b, int N) {
  int n = blockIdx.x;
  int lane = threadIdx.x;
  int h = lane >> 3;       // head owned in accumulate phase
  int sub = lane & 7;
  int hh = lane & 7;       // head owned in logit phase
  __shared__ float sw[64 * 8];
  __shared__ int ssrc[64];
  __shared__ float sm[8], sl[8], sadv[8], smean[8];
  int begin = row_ptr[n], end = row_ptr[n + 1];
  int degr = end - begin;
  if (lane < 8) { sm[lane] = -FLT_MAX; sl[lane] = 0.f; sadv[lane] = adv[(size_t)n * 8 + lane]; }
  float aedsum = 0.f;
  float4 acc = make_float4(0.f, 0.f, 0.f, 0.f);
  for (int cs = begin; cs < end; cs += 64) {
    int c = min(64, end - cs);
    __syncthreads();
    if (lane < c) ssrc[lane] = *(const int*)(rec + (size_t)(cs + lane) * 32);
    __syncthreads();
    for (int idx = lane; idx < c * 8; idx += 64) {
      int el = idx >> 3;
      float ae = __half2float(*(const __half*)(rec + (size_t)(cs + el) * 32 + 4 + hh * 2));
      aedsum += ae;
      float a = asv[(size_t)ssrc[el] * 8 + hh] + sadv[hh] + ae;
      a = a > 0.f ? a : 0.2f * a;
      sw[idx] = a;
    }
    __syncthreads();
    float mloc = -FLT_MAX;
    for (int el = sub; el < c; el += 8) mloc = fmaxf(mloc, sw[el * 8 + h]);
#pragma unroll
    for (int o = 1; o < 8; o <<= 1) mloc = fmaxf(mloc, __shfl_xor(mloc, o));
    float mold = sm[h];
    float mnew = fmaxf(mold, mloc);
    float scale = __expf(mold - mnew);
    float lloc = 0.f;
    for (int el = sub; el < c; el += 8) {
      float w = __expf(sw[el * 8 + h] - mnew);
      sw[el * 8 + h] = w;
      lloc += w;
    }
#pragma unroll
    for (int o = 1; o < 8; o <<= 1) lloc += __shfl_xor(lloc, o);
    __syncthreads();
    if (sub == 0) { sm[h] = mnew; sl[h] = sl[h] * scale + lloc; }
    acc.x *= scale; acc.y *= scale; acc.z *= scale; acc.w *= scale;
#pragma unroll 2
    for (int el = 0; el < c; el++) {
      float w = sw[el * 8 + h];
      ushort4 hv = *(const ushort4*)(h1b + (size_t)ssrc[el] * 256 + lane * 4);
      acc.x += w * bf2f(hv.x);
      acc.y += w * bf2f(hv.y);
      acc.z += w * bf2f(hv.z);
      acc.w += w * bf2f(hv.w);
    }
  }
  // per-head aed mean
  aedsum += __shfl_xor(aedsum, 8);
  aedsum += __shfl_xor(aedsum, 16);
  aedsum += __shfl_xor(aedsum, 32);
  float invd = 1.f / (float)(degr > 1 ? degr : 1);
  if (lane < 8) smean[lane] = aedsum * invd;
  __syncthreads();
  // merged self-loop step
  float a_self = asv[(size_t)n * 8 + h] + sadv[h] + smean[h];
  a_self = a_self > 0.f ? a_self : 0.2f * a_self;
  float mold = sm[h];
  float mnew = fmaxf(mold, a_self);
  float scale = __expf(mold - mnew);
  float w_self = __expf(a_self - mnew);
  float l_fin = sl[h] * scale + w_self;
  ushort4 hs = *(const ushort4*)(h1b + (size_t)n * 256 + lane * 4);
  acc.x = acc.x * scale + w_self * bf2f(hs.x);
  acc.y = acc.y * scale + w_self * bf2f(hs.y);
  acc.z = acc.z * scale + w_self * bf2f(hs.z);
  acc.w = acc.w * scale + w_self * bf2f(hs.w);
  float inv = 1.f / (l_fin + 1e-16f);
  float4 bv = *(const float4*)(b1 + lane * 4);
  ushort4 o4;
  o4.x = f2bf(fmaxf(acc.x * inv + bv.x, 0.f));
  o4.y = f2bf(fmaxf(acc.y * inv + bv.y, 0.f));
  o4.z = f2bf(fmaxf(acc.z * inv + bv.z, 0.f));
  o4.w = f2bf(fmaxf(acc.w * inv + bv.w, 0.f));
  *(ushort4*)(h2b + (size_t)n * 256 + lane * 4) = o4;
}

// g2 = h2 @ W2 (256 -> 32), 8 nodes/block; fused asv2/adv2 epilogue.
__global__ __launch_bounds__(256) void k_gemm2(const ushort* __restrict__ h2b,
                                               const float* __restrict__ W2,
                                               const float* __restrict__ as2,
                                               const float* __restrict__ ad2,
                                               float* __restrict__ g2,
                                               float* __restrict__ asv2,
                                               float* __restrict__ adv2, int N) {
  __shared__ float xs[8 * 256];
  __shared__ float sas[32], sad[32];
  int t = threadIdx.x;
  if (t < 32) { sas[t] = as2[t]; sad[t] = ad2[t]; }
  int n0 = blockIdx.x * 8;
  for (int idx = t; idx < 8 * 256; idx += 256) {
    int node = n0 + (idx >> 8);
    xs[idx] = (node < N) ? bf2f(h2b[(size_t)node * 256 + (idx & 255)]) : 0.f;
  }
  __syncthreads();
  int j = t >> 5, cc = t & 31;
  int node = n0 + j;
  float acc = 0.f;
#pragma unroll 8
  for (int k = 0; k < 256; k++) acc += xs[j * 256 + k] * W2[k * 32 + cc];
  float s1 = acc * sas[cc], s2 = acc * sad[cc];
#pragma unroll
  for (int o = 1; o < 32; o <<= 1) {
    s1 += __shfl_xor(s1, o);
    s2 += __shfl_xor(s2, o);
  }
  if (node < N) {
    g2[(size_t)node * 32 + cc] = acc;
    if (cc == 0) { asv2[node] = s1; adv2[node] = s2; }
  }
}

// ------------------------------------------------- conv2: one wave per node (LDS-staged)
__global__ __launch_bounds__(64) void k_conv2(
    const int* __restrict__ row_ptr, const char* __restrict__ rec,
    const float* __restrict__ asv2, const float* __restrict__ adv2,
    const float* __restrict__ g2, const float* __restrict__ b2,
    float* __restrict__ out, int N) {
  int n = blockIdx.x;
  int lane = threadIdx.x;
  int sub = lane >> 3, q = lane & 7;
  __shared__ float sw[64];
  __shared__ int ssrc[64];
  int begin = row_ptr[n], end = row_ptr[n + 1];
  int degr = end - begin;
  float advn = adv2[n];
  float m = -FLT_MAX, l = 0.f, aedsum = 0.f;
  float4 acc = make_float4(0.f, 0.f, 0.f, 0.f);
  for (int cs = begin; cs < end; cs += 64) {
    int c = min(64, end - cs);
    __syncthreads();
    float a = -FLT_MAX;
    if (lane < c) {
      const char* rp = rec + (size_t)(cs + lane) * 32;
      int s = *(const int*)rp;
      ssrc[lane] = s;
      float ae = *(const float*)(rp + 20);
      aedsum += ae;
      a = asv2[s] + advn + ae;
      a = a > 0.f ? a : 0.2f * a;
    }
    float cm = a;
#pragma unroll
    for (int o = 1; o < 64; o <<= 1) cm = fmaxf(cm, __shfl_xor(cm, o));
    float nm = fmaxf(m, cm);
    float sc = __expf(m - nm);
    float w = (lane < c) ? __expf(a - nm) : 0.f;
    float cl = w;
#pragma unroll
    for (int o = 1; o < 64; o <<= 1) cl += __shfl_xor(cl, o);
    l = l * sc + cl;
    m = nm;
    sw[lane] = w;
    __syncthreads();
    acc.x *= sc; acc.y *= sc; acc.z *= sc; acc.w *= sc;
    for (int el = sub; el < c; el += 8) {
      float w2 = sw[el];
      const float4 gv = *(const float4*)(g2 + (size_t)ssrc[el] * 32 + q * 4);
      acc.x += w2 * gv.x; acc.y += w2 * gv.y; acc.z += w2 * gv.z; acc.w += w2 * gv.w;
    }
  }
  // self-loop merge
#pragma unroll
  for (int o = 1; o < 64; o <<= 1) aedsum += __shfl_xor(aedsum, o);
  float invd = 1.f / (float)(degr > 1 ? degr : 1);
  float a_self = asv2[n] + advn + aedsum * invd;
  a_self = a_self > 0.f ? a_self : 0.2f * a_self;
  float nm = fmaxf(m, a_self);
  float sc = __expf(m - nm);
  float w_self = __expf(a_self - nm);
  l = l * sc + w_self;
  acc.x *= sc; acc.y *= sc; acc.z *= sc; acc.w *= sc;
  if (sub == 0) {
    const float4 gv = *(const float4*)(g2 + (size_t)n * 32 + q * 4);
    acc.x += w_self * gv.x; acc.y += w_self * gv.y;
    acc.z += w_self * gv.z; acc.w += w_self * gv.w;
  }
#pragma unroll
  for (int o = 8; o < 64; o <<= 1) {
    acc.x += __shfl_xor(acc.x, o);
    acc.y += __shfl_xor(acc.y, o);
    acc.z += __shfl_xor(acc.z, o);
    acc.w += __shfl_xor(acc.w, o);
  }
  if (lane < 8) {
    float inv = 1.f / (l + 1e-16f);
    float4 bv = *(const float4*)(b2 + lane * 4);
    float4 o4;
    o4.x = acc.x * inv + bv.x;
    o4.y = acc.y * inv + bv.y;
    o4.z = acc.z * inv + bv.z;
    o4.w = acc.w * inv + bv.w;
    *(float4*)(out + (size_t)n * 32 + lane * 4) = o4;
  }
}

// ---------------------------------------------------------------- launch
extern "C" void kernel_launch(void* const* d_in, const int* in_sizes, int n_in,
                              void* d_out, int out_size, void* d_ws, size_t ws_size,
                              hipStream_t stream) {
  (void)n_in; (void)out_size; (void)ws_size;
  const float* x   = (const float*)d_in[0];
  const int*   ei  = (const int*)d_in[1];
  const float* ea  = (const float*)d_in[2];
  const float* Wse = (const float*)d_in[3];
  const float* bse = (const float*)d_in[4];
  const float* W1  = (const float*)d_in[5];
  const float* as1 = (const float*)d_in[6];
  const float* ad1 = (const float*)d_in[7];
  const float* We1 = (const float*)d_in[8];
  const float* ae1 = (const float*)d_in[9];
  const float* b1  = (const float*)d_in[10];
  const float* W2  = (const float*)d_in[11];
  const float* as2 = (const float*)d_in[12];
  const float* ad2 = (const float*)d_in[13];
  const float* We2 = (const float*)d_in[14];
  const float* ae2 = (const float*)d_in[15];
  const float* b2  = (const float*)d_in[16];
  const int N = in_sizes[0] / 256;
  const int E = in_sizes[1] / 2;
  const int* src = ei;
  const int* dst = ei + E;

  char* base = (char*)d_ws;
  size_t off = 0;
  auto alloc = [&](size_t bytes) -> char* {
    off = (off + 255) & ~(size_t)255;
    char* p = base + off;
    off += bytes;
    return p;
  };
  int*   deg      = (int*)alloc((size_t)N * 4);
  int*   cursor   = (int*)alloc((size_t)N * 4);
  int* row_ptr    = (int*)alloc((size_t)(N + 1) * 4);
  char* rec       = alloc((size_t)E * 32);
  ushort* W1T     = (ushort*)alloc((size_t)256 * 256 * 2);
  ushort* h1b     = (ushort*)alloc((size_t)N * 256 * 2);
  float* asv1     = (float*)alloc((size_t)N * 8 * 4);
  float* adv1     = (float*)alloc((size_t)N * 8 * 4);
  ushort* h2b     = (ushort*)alloc((size_t)N * 256 * 2);
  float* g2       = (float*)alloc((size_t)N * 32 * 4);
  float* asv2     = (float*)alloc((size_t)N * 4);
  float* adv2     = (float*)alloc((size_t)N * 4);
  float* M1       = (float*)alloc(64 * 4);
  float* m2       = (float*)alloc(8 * 4);

  const int DB = (E + 255) / 256;
  hipMemsetAsync(deg, 0, (size_t)N * 4, stream);
  k_pre<<<DB + 65, 256, 0, stream>>>(dst, W1, We1, ae1, We2, ae2, deg, W1T, M1, m2, E, DB);
  k_scan<<<1, 1024, 0, stream>>>(deg, row_ptr, cursor, N);
  k_scatter<<<DB, 256, 0, stream>>>(src, dst, ea, Wse, bse, M1, m2, row_ptr, cursor,
                                    rec, E);
  k_gemm1_mfma<<<(N + 63) / 64, 256, 0, stream>>>(x, W1T, as1, ad1, h1b, asv1, adv1, N);
  k_conv1<<<N, 64, 0, stream>>>(row_ptr, rec, asv1, adv1, h1b, b1, h2b, N);
  k_gemm2<<<(N + 7) / 8, 256, 0, stream>>>(h2b, W2, as2, ad2, g2, asv2, adv2, N);
  k_conv2<<<N, 64, 0, stream>>>(row_ptr, rec, asv2, adv2, g2, b2, (float*)d_out, N);
}

// Round 11
// 227.817 us; speedup vs baseline: 1.2161x; 1.1247x over previous
//
#include <hip/hip_runtime.h>
#include <hip/hip_bf16.h>
#include <hip/hip_fp16.h>
#include <float.h>

// Model constants: N=20000, E=320000, F_IN=256, HID=32, HEADS=8, EDGE_DIM=8
// Edge record (32 B): [0] src:int, [4..20) aed1: 8 x f16, [20] aed2: f32, pad.

typedef short v8s __attribute__((ext_vector_type(8)));
typedef float v4f __attribute__((ext_vector_type(4)));

__device__ __forceinline__ ushort f2bf(float f) {
  unsigned u = __float_as_uint(f);
  u = (u + 0x7FFF + ((u >> 16) & 1)) >> 16;
  return (ushort)u;
}
__device__ __forceinline__ float bf2f(ushort h) {
  return __uint_as_float(((unsigned)h) << 16);
}
__device__ __forceinline__ unsigned pk2bf(float lo, float hi) {
  return (unsigned)f2bf(lo) | ((unsigned)f2bf(hi) << 16);
}
__device__ __forceinline__ unsigned pk2h(float lo, float hi) {
  return (unsigned)__half_as_ushort(__float2half(lo)) |
         ((unsigned)__half_as_ushort(__float2half(hi)) << 16);
}

// ---- k_pre: deg count + W1 transpose + M1/m2 prep + W2 blocked transpose
// blocks [0,DB): deg; [DB,DB+64): W1->W1T; DB+64: M1/m2 + W2B.
__global__ __launch_bounds__(256) void k_pre(const int* __restrict__ dst,
                                             const float* __restrict__ W1,
                                             const float* __restrict__ We1,
                                             const float* __restrict__ ae1,
                                             const float* __restrict__ We2,
                                             const float* __restrict__ ae2,
                                             const float* __restrict__ W2,
                                             int* __restrict__ deg,
                                             ushort* __restrict__ Bt,
                                             float* __restrict__ M1,
                                             float* __restrict__ m2,
                                             float* __restrict__ W2B,
                                             int E, int DB) {
  int b = blockIdx.x;
  if (b < DB) {
    int e = b * 256 + threadIdx.x;
    if (e < E) atomicAdd(&deg[dst[e]], 1);
    return;
  }
  if (b == DB + 64) {
    int t = threadIdx.x;
    // W2B[(k>>2)*128 + cc*4 + (k&3)] = W2[k][cc]
    for (int i = t; i < 8192; i += 256) {
      int k = i >> 5, cc = i & 31;
      W2B[(size_t)(k >> 2) * 128 + cc * 4 + (k & 3)] = W2[(size_t)k * 32 + cc];
    }
    if (t < 64) {
      int k = t >> 3, h = t & 7;
      float s = 0.f;
      for (int c = 0; c < 32; c++) s += We1[k * 256 + h * 32 + c] * ae1[h * 32 + c];
      M1[k * 8 + h] = s;
    } else if (t < 72) {
      int k = t - 64;
      float s = 0.f;
      for (int c = 0; c < 32; c++) s += We2[k * 32 + c] * ae2[c];
      m2[k] = s;
    }
    return;
  }
  int b2 = b - DB;
  __shared__ float tile[32][33];
  int bx = b2 & 7, by = b2 >> 3;
  int tx = threadIdx.x & 31, ty = threadIdx.x >> 5;
  for (int r = ty; r < 32; r += 8)
    tile[r][tx] = W1[(size_t)(by * 32 + r) * 256 + bx * 32 + tx];
  __syncthreads();
  for (int r = ty; r < 32; r += 8)
    Bt[(size_t)(bx * 32 + r) * 256 + by * 32 + tx] = f2bf(tile[tx][r]);
}

// ---------------------------------------------------------------- CSR build
__global__ __launch_bounds__(1024) void k_scan(const int* __restrict__ deg,
                                               int* __restrict__ row_ptr,
                                               int* __restrict__ cursor, int N) {
  __shared__ int part[1024];
  int tid = threadIdx.x;
  int chunk = (N + 1023) / 1024;
  int lo = tid * chunk;
  if (lo > N) lo = N;
  int hi = lo + chunk;
  if (hi > N) hi = N;
  int s = 0;
  for (int i = lo; i < hi; i++) { s += deg[i]; cursor[i] = 0; }
  part[tid] = s;
  __syncthreads();
  for (int off = 1; off < 1024; off <<= 1) {
    int v = 0;
    if (tid >= off) v = part[tid - off];
    __syncthreads();
    part[tid] += v;
    __syncthreads();
  }
  int base = part[tid] - s;  // exclusive prefix
  for (int i = lo; i < hi; i++) { row_ptr[i] = base; base += deg[i]; }
  if (tid == 1023) row_ptr[N] = part[1023];
}

// ---- k_mega1: blocks [0,GB) = MFMA gemm1 (+fused attn1); [GB,GB+DB) = scatter.
// Independent workloads co-scheduled so scatter's atomic latency hides under MFMA.
__global__ __launch_bounds__(256) void k_mega1(
    // gemm1 args
    const float* __restrict__ A, const ushort* __restrict__ Bt,
    const float* __restrict__ as1, const float* __restrict__ ad1,
    ushort* __restrict__ h1b, float* __restrict__ asv, float* __restrict__ adv, int M,
    // scatter args
    const int* __restrict__ src, const int* __restrict__ dst,
    const float* __restrict__ ea, const float* __restrict__ Wse,
    const float* __restrict__ bse, const float* __restrict__ M1,
    const float* __restrict__ m2, const int* __restrict__ row_ptr,
    int* __restrict__ cursor, char* __restrict__ rec, int E, int GB) {
  __shared__ __align__(16) char smem[27648];
  int t = threadIdx.x;
  if (blockIdx.x >= GB) {
    // ---------------- scatter path ----------------
    float* sW  = (float*)smem;        // 16
    float* sbv = sW + 16;             // 8
    float* sM  = sbv + 8;             // 64
    float* sm2 = sM + 64;             // 8
    if (t < 16) sW[t] = Wse[t];
    if (t < 8) sbv[t] = bse[t];
    if (t < 64) sM[t] = M1[t];
    if (t >= 64 && t < 72) sm2[t - 64] = m2[t - 64];
    __syncthreads();
    int i = (blockIdx.x - GB) * 256 + t;
    if (i >= E) return;
    float2 av = ((const float2*)ea)[i];
    float e8[8];
#pragma unroll
    for (int k = 0; k < 8; k++)
      e8[k] = fmaxf(av.x * sW[k] + av.y * sW[8 + k] + sbv[k], 0.f);
    float o[8];
#pragma unroll
    for (int h = 0; h < 8; h++) {
      float s = 0.f;
#pragma unroll
      for (int k = 0; k < 8; k++) s += e8[k] * sM[k * 8 + h];
      o[h] = s;
    }
    float s2 = 0.f;
#pragma unroll
    for (int k = 0; k < 8; k++) s2 += e8[k] * sm2[k];
    int d = dst[i];
    int pos = row_ptr[d] + atomicAdd(&cursor[d], 1);
    uint4 w0, w1;
    w0.x = (unsigned)src[i];
    w0.y = pk2h(o[0], o[1]);
    w0.z = pk2h(o[2], o[3]);
    w0.w = pk2h(o[4], o[5]);
    w1.x = pk2h(o[6], o[7]);
    w1.y = __float_as_uint(s2);
    w1.z = 0; w1.w = 0;
    *(uint4*)(rec + (size_t)pos * 32)      = w0;
    *(uint4*)(rec + (size_t)pos * 32 + 16) = w1;
    return;
  }
  // ---------------- gemm1 path ----------------
  ushort* sA = (ushort*)smem;             // 64*40*2   = 5120
  ushort* sB = (ushort*)(smem + 5120);    // 256*40*2  = 20480
  float* sas = (float*)(smem + 25600);    // 1024
  float* sad = (float*)(smem + 26624);    // 1024
  int wave = t >> 6, lane = t & 63;
  int m0 = blockIdx.x * 64;
  int c = lane & 15, kg = lane >> 4;
  sas[t] = as1[t];
  sad[t] = ad1[t];
  v4f acc[4][4];
#pragma unroll
  for (int a = 0; a < 4; a++)
#pragma unroll
    for (int b = 0; b < 4; b++) acc[a][b] = (v4f)(0.f);
  int arow = t >> 2;
  int akoff = (t & 3) * 8;
  bool aval = (m0 + arow) < M;
  const float* aptr = A + (size_t)(m0 + arow) * 256 + akoff;
  const ushort* bptr = Bt + (size_t)t * 256;
  for (int k0 = 0; k0 < 256; k0 += 32) {
    float4 v0 = make_float4(0.f, 0.f, 0.f, 0.f), v1 = v0;
    if (aval) { v0 = *(const float4*)(aptr + k0); v1 = *(const float4*)(aptr + k0 + 4); }
    unsigned* dst32 = (unsigned*)&sA[arow * 40 + akoff];
    dst32[0] = pk2bf(v0.x, v0.y);
    dst32[1] = pk2bf(v0.z, v0.w);
    dst32[2] = pk2bf(v1.x, v1.y);
    dst32[3] = pk2bf(v1.z, v1.w);
    *(v8s*)&sB[t * 40 + 0]  = *(const v8s*)(bptr + k0 + 0);
    *(v8s*)&sB[t * 40 + 8]  = *(const v8s*)(bptr + k0 + 8);
    *(v8s*)&sB[t * 40 + 16] = *(const v8s*)(bptr + k0 + 16);
    *(v8s*)&sB[t * 40 + 24] = *(const v8s*)(bptr + k0 + 24);
    __syncthreads();
    v8s af[4], bfr[4];
#pragma unroll
    for (int mt = 0; mt < 4; mt++) af[mt] = *(v8s*)&sA[(mt * 16 + c) * 40 + kg * 8];
#pragma unroll
    for (int nt = 0; nt < 4; nt++) bfr[nt] = *(v8s*)&sB[(wave * 64 + nt * 16 + c) * 40 + kg * 8];
#pragma unroll
    for (int mt = 0; mt < 4; mt++)
#pragma unroll
      for (int nt = 0; nt < 4; nt++)
        acc[mt][nt] = __builtin_amdgcn_mfma_f32_16x16x32_bf16(af[mt], bfr[nt], acc[mt][nt], 0, 0, 0);
    __syncthreads();
  }
  int colbase = wave * 64;
#pragma unroll
  for (int mt = 0; mt < 4; mt++) {
#pragma unroll
    for (int i = 0; i < 4; i++) {
      int m = m0 + mt * 16 + kg * 4 + i;
      if (m < M) {
#pragma unroll
        for (int nt = 0; nt < 4; nt++)
          h1b[(size_t)m * 256 + colbase + nt * 16 + c] = f2bf(acc[mt][nt][i]);
      }
      float s1a = acc[mt][0][i] * sas[colbase + c]      + acc[mt][1][i] * sas[colbase + 16 + c];
      float s2a = acc[mt][0][i] * sad[colbase + c]      + acc[mt][1][i] * sad[colbase + 16 + c];
      float s1b = acc[mt][2][i] * sas[colbase + 32 + c] + acc[mt][3][i] * sas[colbase + 48 + c];
      float s2b = acc[mt][2][i] * sad[colbase + 32 + c] + acc[mt][3][i] * sad[colbase + 48 + c];
#pragma unroll
      for (int o = 1; o < 16; o <<= 1) {
        s1a += __shfl_xor(s1a, o);
        s2a += __shfl_xor(s2a, o);
        s1b += __shfl_xor(s1b, o);
        s2b += __shfl_xor(s2b, o);
      }
      if (c == 0 && m < M) {
        asv[(size_t)m * 8 + 2 * wave]     = s1a;
        adv[(size_t)m * 8 + 2 * wave]     = s2a;
        asv[(size_t)m * 8 + 2 * wave + 1] = s1b;
        adv[(size_t)m * 8 + 2 * wave + 1] = s2b;
      }
    }
  }
}

// ---- conv1 (wave per node) with fused gemm2 epilogue:
// computes h2 row (fp32, in LDS), then g2 = h2@W2 via W2B, asv2/adv2 via shuffles.
__global__ __launch_bounds__(64) void k_conv1(
    const int* __restrict__ row_ptr, const char* __restrict__ rec,
    const float* __restrict__ asv, const float* __restrict__ adv,
    const ushort* __restrict__ h1b, const float* __restrict__ b1,
    const float* __restrict__ W2B, const float* __restrict__ as2,
    const float* __restrict__ ad2, float* __restrict__ g2,
    float* __restrict__ asv2, float* __restrict__ adv2, int N) {
  int n = blockIdx.x;
  int lane = threadIdx.x;
  int h = lane >> 3;       // head owned in accumulate phase
  int sub = lane & 7;
  int hh = lane & 7;       // head owned in logit phase
  __shared__ float sw[64 * 8];
  __shared__ int ssrc[64];
  __shared__ float sm[8], sl[8], sadv[8], smean[8];
  __shared__ float sh2[256];
  int begin = row_ptr[n], end = row_ptr[n + 1];
  int degr = end - begin;
  if (lane < 8) { sm[lane] = -FLT_MAX; sl[lane] = 0.f; sadv[lane] = adv[(size_t)n * 8 + lane]; }
  float aedsum = 0.f;
  float4 acc = make_float4(0.f, 0.f, 0.f, 0.f);
  for (int cs = begin; cs < end; cs += 64) {
    int c = min(64, end - cs);
    __syncthreads();
    if (lane < c) ssrc[lane] = *(const int*)(rec + (size_t)(cs + lane) * 32);
    __syncthreads();
    for (int idx = lane; idx < c * 8; idx += 64) {
      int el = idx >> 3;
      float ae = __half2float(*(const __half*)(rec + (size_t)(cs + el) * 32 + 4 + hh * 2));
      aedsum += ae;
      float a = asv[(size_t)ssrc[el] * 8 + hh] + sadv[hh] + ae;
      a = a > 0.f ? a : 0.2f * a;
      sw[idx] = a;
    }
    __syncthreads();
    float mloc = -FLT_MAX;
    for (int el = sub; el < c; el += 8) mloc = fmaxf(mloc, sw[el * 8 + h]);
#pragma unroll
    for (int o = 1; o < 8; o <<= 1) mloc = fmaxf(mloc, __shfl_xor(mloc, o));
    float mold = sm[h];
    float mnew = fmaxf(mold, mloc);
    float scale = __expf(mold - mnew);
    float lloc = 0.f;
    for (int el = sub; el < c; el += 8) {
      float w = __expf(sw[el * 8 + h] - mnew);
      sw[el * 8 + h] = w;
      lloc += w;
    }
#pragma unroll
    for (int o = 1; o < 8; o <<= 1) lloc += __shfl_xor(lloc, o);
    __syncthreads();
    if (sub == 0) { sm[h] = mnew; sl[h] = sl[h] * scale + lloc; }
    acc.x *= scale; acc.y *= scale; acc.z *= scale; acc.w *= scale;
#pragma unroll 2
    for (int el = 0; el < c; el++) {
      float w = sw[el * 8 + h];
      ushort4 hv = *(const ushort4*)(h1b + (size_t)ssrc[el] * 256 + lane * 4);
      acc.x += w * bf2f(hv.x);
      acc.y += w * bf2f(hv.y);
      acc.z += w * bf2f(hv.z);
      acc.w += w * bf2f(hv.w);
    }
  }
  // per-head aed mean
  aedsum += __shfl_xor(aedsum, 8);
  aedsum += __shfl_xor(aedsum, 16);
  aedsum += __shfl_xor(aedsum, 32);
  float invd = 1.f / (float)(degr > 1 ? degr : 1);
  if (lane < 8) smean[lane] = aedsum * invd;
  __syncthreads();
  // merged self-loop step
  float a_self = asv[(size_t)n * 8 + h] + sadv[h] + smean[h];
  a_self = a_self > 0.f ? a_self : 0.2f * a_self;
  float mold = sm[h];
  float mnew = fmaxf(mold, a_self);
  float scale = __expf(mold - mnew);
  float w_self = __expf(a_self - mnew);
  float l_fin = sl[h] * scale + w_self;
  ushort4 hs = *(const ushort4*)(h1b + (size_t)n * 256 + lane * 4);
  acc.x = acc.x * scale + w_self * bf2f(hs.x);
  acc.y = acc.y * scale + w_self * bf2f(hs.y);
  acc.z = acc.z * scale + w_self * bf2f(hs.z);
  acc.w = acc.w * scale + w_self * bf2f(hs.w);
  float inv = 1.f / (l_fin + 1e-16f);
  float4 bv = *(const float4*)(b1 + lane * 4);
  float4 h2v;
  h2v.x = fmaxf(acc.x * inv + bv.x, 0.f);
  h2v.y = fmaxf(acc.y * inv + bv.y, 0.f);
  h2v.z = fmaxf(acc.z * inv + bv.z, 0.f);
  h2v.w = fmaxf(acc.w * inv + bv.w, 0.f);
  *(float4*)&sh2[lane * 4] = h2v;
  __syncthreads();
  // fused gemm2: g2[cc] = sum_k h2[k] * W2[k][cc]; halves split k-range.
  int half = lane >> 5, cc = lane & 31;
  const float* wp = W2B + (size_t)half * 32 * 128 + cc * 4;
  const float* hp2 = sh2 + half * 128;
  float part = 0.f;
#pragma unroll 8
  for (int g = 0; g < 32; g++) {
    float4 wv = *(const float4*)(wp + g * 128);
    float4 hv = *(const float4*)(hp2 + g * 4);
    part += wv.x * hv.x + wv.y * hv.y + wv.z * hv.z + wv.w * hv.w;
  }
  part += __shfl_xor(part, 32);
  float s1 = part * as2[cc];
  float s2 = part * ad2[cc];
#pragma unroll
  for (int o = 1; o < 32; o <<= 1) {
    s1 += __shfl_xor(s1, o);
    s2 += __shfl_xor(s2, o);
  }
  if (lane < 32) g2[(size_t)n * 32 + cc] = part;
  if (lane == 0) { asv2[n] = s1; adv2[n] = s2; }
}

// ------------------------------------------------- conv2: one wave per node (LDS-staged)
__global__ __launch_bounds__(64) void k_conv2(
    const int* __restrict__ row_ptr, const char* __restrict__ rec,
    const float* __restrict__ asv2, const float* __restrict__ adv2,
    const float* __restrict__ g2, const float* __restrict__ b2,
    float* __restrict__ out, int N) {
  int n = blockIdx.x;
  int lane = threadIdx.x;
  int sub = lane >> 3, q = lane & 7;
  __shared__ float sw[64];
  __shared__ int ssrc[64];
  int begin = row_ptr[n], end = row_ptr[n + 1];
  int degr = end - begin;
  float advn = adv2[n];
  float m = -FLT_MAX, l = 0.f, aedsum = 0.f;
  float4 acc = make_float4(0.f, 0.f, 0.f, 0.f);
  for (int cs = begin; cs < end; cs += 64) {
    int c = min(64, end - cs);
    __syncthreads();
    float a = -FLT_MAX;
    if (lane < c) {
      const char* rp = rec + (size_t)(cs + lane) * 32;
      int s = *(const int*)rp;
      ssrc[lane] = s;
      float ae = *(const float*)(rp + 20);
      aedsum += ae;
      a = asv2[s] + advn + ae;
      a = a > 0.f ? a : 0.2f * a;
    }
    float cm = a;
#pragma unroll
    for (int o = 1; o < 64; o <<= 1) cm = fmaxf(cm, __shfl_xor(cm, o));
    float nm = fmaxf(m, cm);
    float sc = __expf(m - nm);
    float w = (lane < c) ? __expf(a - nm) : 0.f;
    float cl = w;
#pragma unroll
    for (int o = 1; o < 64; o <<= 1) cl += __shfl_xor(cl, o);
    l = l * sc + cl;
    m = nm;
    sw[lane] = w;
    __syncthreads();
    acc.x *= sc; acc.y *= sc; acc.z *= sc; acc.w *= sc;
    for (int el = sub; el < c; el += 8) {
      float w2 = sw[el];
      const float4 gv = *(const float4*)(g2 + (size_t)ssrc[el] * 32 + q * 4);
      acc.x += w2 * gv.x; acc.y += w2 * gv.y; acc.z += w2 * gv.z; acc.w += w2 * gv.w;
    }
  }
  // self-loop merge
#pragma unroll
  for (int o = 1; o < 64; o <<= 1) aedsum += __shfl_xor(aedsum, o);
  float invd = 1.f / (float)(degr > 1 ? degr : 1);
  float a_self = asv2[n] + advn + aedsum * invd;
  a_self = a_self > 0.f ? a_self : 0.2f * a_self;
  float nm = fmaxf(m, a_self);
  float sc = __expf(m - nm);
  float w_self = __expf(a_self - nm);
  l = l * sc + w_self;
  acc.x *= sc; acc.y *= sc; acc.z *= sc; acc.w *= sc;
  if (sub == 0) {
    const float4 gv = *(const float4*)(g2 + (size_t)n * 32 + q * 4);
    acc.x += w_self * gv.x; acc.y += w_self * gv.y;
    acc.z += w_self * gv.z; acc.w += w_self * gv.w;
  }
#pragma unroll
  for (int o = 8; o < 64; o <<= 1) {
    acc.x += __shfl_xor(acc.x, o);
    acc.y += __shfl_xor(acc.y, o);
    acc.z += __shfl_xor(acc.z, o);
    acc.w += __shfl_xor(acc.w, o);
  }
  if (lane < 8) {
    float inv = 1.f / (l + 1e-16f);
    float4 bv = *(const float4*)(b2 + lane * 4);
    float4 o4;
    o4.x = acc.x * inv + bv.x;
    o4.y = acc.y * inv + bv.y;
    o4.z = acc.z * inv + bv.z;
    o4.w = acc.w * inv + bv.w;
    *(float4*)(out + (size_t)n * 32 + lane * 4) = o4;
  }
}

// ---------------------------------------------------------------- launch
extern "C" void kernel_launch(void* const* d_in, const int* in_sizes, int n_in,
                              void* d_out, int out_size, void* d_ws, size_t ws_size,
                              hipStream_t stream) {
  (void)n_in; (void)out_size; (void)ws_size;
  const float* x   = (const float*)d_in[0];
  const int*   ei  = (const int*)d_in[1];
  const float* ea  = (const float*)d_in[2];
  const float* Wse = (const float*)d_in[3];
  const float* bse = (const float*)d_in[4];
  const float* W1  = (const float*)d_in[5];
  const float* as1 = (const float*)d_in[6];
  const float* ad1 = (const float*)d_in[7];
  const float* We1 = (const float*)d_in[8];
  const float* ae1 = (const float*)d_in[9];
  const float* b1  = (const float*)d_in[10];
  const float* W2  = (const float*)d_in[11];
  const float* as2 = (const float*)d_in[12];
  const float* ad2 = (const float*)d_in[13];
  const float* We2 = (const float*)d_in[14];
  const float* ae2 = (const float*)d_in[15];
  const float* b2  = (const float*)d_in[16];
  const int N = in_sizes[0] / 256;
  const int E = in_sizes[1] / 2;
  const int* src = ei;
  const int* dst = ei + E;

  char* base = (char*)d_ws;
  size_t off = 0;
  auto alloc = [&](size_t bytes) -> char* {
    off = (off + 255) & ~(size_t)255;
    char* p = base + off;
    off += bytes;
    return p;
  };
  int*   deg      = (int*)alloc((size_t)N * 4);
  int*   cursor   = (int*)alloc((size_t)N * 4);
  int* row_ptr    = (int*)alloc((size_t)(N + 1) * 4);
  char* rec       = alloc((size_t)E * 32);
  ushort* W1T     = (ushort*)alloc((size_t)256 * 256 * 2);
  float* W2B      = (float*)alloc((size_t)256 * 32 * 4);
  ushort* h1b     = (ushort*)alloc((size_t)N * 256 * 2);
  float* asv1     = (float*)alloc((size_t)N * 8 * 4);
  float* adv1     = (float*)alloc((size_t)N * 8 * 4);
  float* g2       = (float*)alloc((size_t)N * 32 * 4);
  float* asv2     = (float*)alloc((size_t)N * 4);
  float* adv2     = (float*)alloc((size_t)N * 4);
  float* M1       = (float*)alloc(64 * 4);
  float* m2       = (float*)alloc(8 * 4);

  const int DB = (E + 255) / 256;
  const int GB = (N + 63) / 64;
  hipMemsetAsync(deg, 0, (size_t)N * 4, stream);
  k_pre<<<DB + 65, 256, 0, stream>>>(dst, W1, We1, ae1, We2, ae2, W2,
                                     deg, W1T, M1, m2, W2B, E, DB);
  k_scan<<<1, 1024, 0, stream>>>(deg, row_ptr, cursor, N);
  k_mega1<<<GB + DB, 256, 0, stream>>>(x, W1T, as1, ad1, h1b, asv1, adv1, N,
                                       src, dst, ea, Wse, bse, M1, m2, row_ptr,
                                       cursor, rec, E, GB);
  k_conv1<<<N, 64, 0, stream>>>(row_ptr, rec, asv1, adv1, h1b, b1,
                                W2B, as2, ad2, g2, asv2, adv2, N);
  k_conv2<<<N, 64, 0, stream>>>(row_ptr, rec, asv2, adv2, g2, b2, (float*)d_out, N);
}